// Round 1
// 484.806 us; speedup vs baseline: 1.2897x; 1.2897x over previous
//
#include <hip/hip_runtime.h>

// ============================================================================
// PlasticityModelMoE — MI355X (gfx950). Inputs f32, output f32, bf16 MFMA.
// R8: attack the GEMM parallelism/locality stall (MfmaUtil 6.7%, Occ 23.6%):
//   - GEMM-A and GEMM-C rebuilt as 128x128 split-K partial GEMMs
//     (split=4 -> grid 1024/512, 3-4 blocks/CU instead of 2) + XCD-aware
//     block swizzle for L2 panel locality. f32 partials land in dead
//     workspace regions (rwT/logits lifetime holes) -> no extra peak ws.
//   - epilogues (gate-bias + conn*mask + 8-way act blend; final sum) move to
//     flat, coalesced reduce kernels.
//   - k_gemm_logits keeps its verified 128x128 structure + gains the swizzle.
// ============================================================================

typedef unsigned short u16;
typedef __attribute__((ext_vector_type(8))) short bf16x8;   // 8 bf16 = 4 VGPRs
typedef __attribute__((ext_vector_type(4))) float f32x4;

__device__ __forceinline__ float b2f(u16 h) {
    union { unsigned u; float f; } v; v.u = ((unsigned)h) << 16; return v.f;
}
__device__ __forceinline__ u16 f2b(float f) {
    union { float f; unsigned u; } v; v.f = f;
    unsigned u = v.u;
    return (u16)((u + 0x7fffu + ((u >> 16) & 1u)) >> 16);   // round-nearest-even
}

// async global->LDS, 16B per lane (wave-uniform base + lane*16 — m97 pattern).
__device__ __forceinline__ void async_copy16(void* lds, const void* g) {
    __builtin_amdgcn_global_load_lds(
        (__attribute__((address_space(1))) void*)(g),
        (__attribute__((address_space(3))) void*)(lds), 16, 0, 0);
}

// ---------------------------------------------------------------------------
// Double-buffered GEMM core: C[M,N] += A[M,K]*B[N,K]^T, bf16 in, f32 acc.
// Kloop = K extent to accumulate; ld = row stride (elements) of A and B.
// S stages of BK=32 per barrier window. Two LDS sets; prefetch of window i+1
// issued BEFORE compute of window i; the barrier's vmcnt(0) drain is
// overlapped by that compute.
// 256 thr, 4 waves 2x2, wave tile (BM/2)x(BN/2), mfma_f32_16x16x32_bf16.
// Layouts (m89/m91): A-frag A[m=lane&15][k=(lane>>4)*8+j]; B-frag same (n);
// C/D col(n)=lane&15, row(m)=(lane>>4)*4+reg.
// smem must hold 2 * (BM+BN) * 32 * S u16 elements.
// ---------------------------------------------------------------------------
template<int BM, int BN, int S>
__device__ __forceinline__ void gemm_core_db(const u16* __restrict__ A,
                                             const u16* __restrict__ B,
                                             int Kloop, int ld,
                                             int row0, int col0,
                                             u16* smem,
                                             f32x4 (&acc)[BM / 32][BN / 32])
{
    constexpr int MT = BM / 32, NT = BN / 32;
    constexpr int STG = (BM + BN) * 32;     // u16 per stage
    constexpr int SET = STG * S;            // u16 per buffer set
    const int tid  = threadIdx.x;
    const int lane = tid & 63;
    const int wv   = tid >> 6;
    const int wr   = wv >> 1, wc = wv & 1;
    const int lr   = lane & 15, kg = lane >> 4;

#pragma unroll
    for (int i = 0; i < MT; i++)
#pragma unroll
        for (int j = 0; j < NT; j++) {
            f32x4 z = {0.f, 0.f, 0.f, 0.f};
            acc[i][j] = z;
        }

    auto stage_in = [&](u16* set, int k0) {
#pragma unroll
        for (int c = tid; c < BM * 4; c += 256) {
            const u16* gA = A + (size_t)(row0 + (c >> 2)) * ld + k0 + (c & 3) * 8;
#pragma unroll
            for (int s = 0; s < S; s++)
                async_copy16(set + s * STG + c * 8, gA + s * 32);
        }
#pragma unroll
        for (int c = tid; c < BN * 4; c += 256) {
            const u16* gB = B + (size_t)(col0 + (c >> 2)) * ld + k0 + (c & 3) * 8;
#pragma unroll
            for (int s = 0; s < S; s++)
                async_copy16(set + s * STG + BM * 32 + c * 8, gB + s * 32);
        }
    };

    stage_in(smem, 0);
    __syncthreads();           // drain prologue staging

    int p = 0;
    for (int k0 = 0; k0 < Kloop; k0 += 32 * S) {
        if (k0 + 32 * S < Kloop)
            stage_in(smem + (p ^ 1) * SET, k0 + 32 * S);   // prefetch next window
        u16* set = smem + p * SET;
#pragma unroll
        for (int s = 0; s < S; s++) {
            const u16* sA = set + s * STG;
            const u16* sB = sA + BM * 32;
            bf16x8 af[MT], bfr[NT];
#pragma unroll
            for (int i = 0; i < MT; i++)
                af[i] = *(const bf16x8*)(sA + ((wr * (BM / 2) + i * 16 + lr) * 32 + kg * 8));
#pragma unroll
            for (int j = 0; j < NT; j++)
                bfr[j] = *(const bf16x8*)(sB + ((wc * (BN / 2) + j * 16 + lr) * 32 + kg * 8));
#pragma unroll
            for (int i = 0; i < MT; i++)
#pragma unroll
                for (int j = 0; j < NT; j++)
                    acc[i][j] = __builtin_amdgcn_mfma_f32_16x16x32_bf16(
                                    af[i], bfr[j], acc[i][j], 0, 0, 0);
        }
        __syncthreads();       // one barrier/window; vmcnt drain overlapped above
        p ^= 1;
    }
}

// ---------------------------------------------------------------------------
// tiny: conn = sigmoid(relu(na@W1+b1)@W2+b2), wts = softmax(act_w). All f32.
// ---------------------------------------------------------------------------
__global__ __launch_bounds__(256)
void k_small(const float* __restrict__ na, const float* __restrict__ W1,
             const float* __restrict__ b1, const float* __restrict__ W2,
             const float* __restrict__ b2, const float* __restrict__ actw,
             float* __restrict__ conn, float* __restrict__ wts)
{
    __shared__ float red[256 * 32];
    __shared__ float hsh[32];
    const int tid = threadIdx.x;
    float h[32];
#pragma unroll
    for (int k = 0; k < 32; k++) h[k] = 0.f;
    for (int u = tid; u < 2048; u += 256) {
        float nav = na[u];
        const float* row = W1 + u * 32;
#pragma unroll
        for (int k = 0; k < 32; k++) h[k] += nav * row[k];
    }
#pragma unroll
    for (int k = 0; k < 32; k++) red[tid * 32 + k] = h[k];
    for (int s = 128; s > 0; s >>= 1) {
        __syncthreads();
        if (tid < s)
#pragma unroll
            for (int k = 0; k < 32; k++) red[tid * 32 + k] += red[(tid + s) * 32 + k];
    }
    __syncthreads();
    if (tid < 32) hsh[tid] = fmaxf(red[tid] + b1[tid], 0.f);
    if (tid == 0) {
        float e[9], m = -1e30f;
        for (int i = 0; i < 9; i++) { e[i] = actw[i]; m = fmaxf(m, e[i]); }
        float s = 0.f;
        for (int i = 0; i < 9; i++) { e[i] = expf(e[i] - m); s += e[i]; }
        for (int i = 0; i < 9; i++) wts[i] = e[i] / s;
    }
    __syncthreads();
    for (int u = tid; u < 2048; u += 256) {
        float a = 0.f;
#pragma unroll
        for (int k = 0; k < 32; k++) a += hsh[k] * W2[k * 2048 + u];
        conn[u] = 1.f / (1.f + expf(-(a + b2[u])));
    }
}

// ---------------------------------------------------------------------------
// gate softmax + y = x*gate (bf16 out). One wave per row n.
// ---------------------------------------------------------------------------
__global__ __launch_bounds__(256)
void k_gate_y(const float* __restrict__ x, const float* __restrict__ gW,
              const float* __restrict__ gb, float* __restrict__ gate,
              u16* __restrict__ y)
{
    const int tid = threadIdx.x, lane = tid & 63, wv = tid >> 6;
    const int n = blockIdx.x * 4 + wv;
    const float* xr = x + (size_t)n * 1024;
    float a0 = 0, a1 = 0, a2 = 0, a3 = 0;
    float xv[16];
#pragma unroll
    for (int s = 0; s < 16; s++) {
        int d = s * 64 + lane;
        float xd = xr[d]; xv[s] = xd;
        float4 g4 = *(const float4*)(gW + d * 4);
        a0 += xd * g4.x; a1 += xd * g4.y; a2 += xd * g4.z; a3 += xd * g4.w;
    }
#pragma unroll
    for (int off = 32; off > 0; off >>= 1) {
        a0 += __shfl_xor(a0, off); a1 += __shfl_xor(a1, off);
        a2 += __shfl_xor(a2, off); a3 += __shfl_xor(a3, off);
    }
    a0 += gb[0]; a1 += gb[1]; a2 += gb[2]; a3 += gb[3];
    float m = fmaxf(fmaxf(a0, a1), fmaxf(a2, a3));
    float e0 = expf(a0 - m), e1 = expf(a1 - m), e2 = expf(a2 - m), e3 = expf(a3 - m);
    float inv = 1.f / (e0 + e1 + e2 + e3);
    float g0 = e0 * inv, g1 = e1 * inv, g2 = e2 * inv, g3 = e3 * inv;
    if (lane == 0) *(float4*)(gate + n * 4) = make_float4(g0, g1, g2, g3);
#pragma unroll
    for (int s = 0; s < 16; s++) {
        int d = s * 64 + lane;
        ushort4 o;
        o.x = f2b(xv[s] * g0); o.y = f2b(xv[s] * g1);
        o.z = f2b(xv[s] * g2); o.w = f2b(xv[s] * g3);
        *(ushort4*)(y + (size_t)n * 4096 + d * 4) = o;
    }
}

// ---------------------------------------------------------------------------
// wmT[u, d*4+b] = w[d,u,b] * sigmoid(delay[d,u,b]); f32 in, bf16 out.
// ---------------------------------------------------------------------------
__global__ __launch_bounds__(256)
void k_wmT(const float* __restrict__ w, const float* __restrict__ delay,
           u16* __restrict__ wmT)
{
    __shared__ __align__(16) ushort4 tile[32][65];
    const int tid = threadIdx.x;
    const int tx = tid & 63, ty = tid >> 6;          // tx: u, ty: d-subset
    const int u0 = blockIdx.x * 64, d0 = blockIdx.y * 32;
#pragma unroll
    for (int i = 0; i < 8; i++) {
        int d = i * 4 + ty;
        size_t idx = ((size_t)(d0 + d) * 2048 + (u0 + tx)) * 4;
        float4 w4 = *(const float4*)(w + idx);
        float4 d4 = *(const float4*)(delay + idx);
        ushort4 o;
        o.x = f2b(w4.x / (1.f + expf(-d4.x)));
        o.y = f2b(w4.y / (1.f + expf(-d4.y)));
        o.z = f2b(w4.z / (1.f + expf(-d4.z)));
        o.w = f2b(w4.w / (1.f + expf(-d4.w)));
        tile[d][tx] = o;
    }
    __syncthreads();
    const int dx = tid & 31, uy = tid >> 5;
#pragma unroll
    for (int i = 0; i < 8; i++) {
        int u = i * 8 + uy;
        *(ushort4*)(wmT + (size_t)(u0 + u) * 4096 + (d0 + dx) * 4) = tile[dx][u];
    }
}

// ---------------------------------------------------------------------------
// transpose + cast: in[R,C] f32 -> out[C,R] bf16, 64x64 tiles
// ---------------------------------------------------------------------------
__global__ __launch_bounds__(256)
void k_transpose(const float* __restrict__ in, u16* __restrict__ out, int R, int C)
{
    __shared__ __align__(16) u16 t[64][68];
    const int tid = threadIdx.x, tx = tid & 15, ty = tid >> 4;
    const int c0 = blockIdx.x * 64, r0 = blockIdx.y * 64;
#pragma unroll
    for (int i = 0; i < 4; i++) {
        int r = r0 + ty + i * 16;
        float4 v = *(const float4*)(in + (size_t)r * C + c0 + tx * 4);
        t[tx * 4 + 0][ty + i * 16] = f2b(v.x); t[tx * 4 + 1][ty + i * 16] = f2b(v.y);
        t[tx * 4 + 2][ty + i * 16] = f2b(v.z); t[tx * 4 + 3][ty + i * 16] = f2b(v.w);
    }
    __syncthreads();
#pragma unroll
    for (int i = 0; i < 4; i++) {
        int c = ty + i * 16;
        ushort4 v;
        v.x = t[c][tx * 4 + 0]; v.y = t[c][tx * 4 + 1];
        v.z = t[c][tx * 4 + 2]; v.w = t[c][tx * 4 + 3];
        *(ushort4*)(out + (size_t)(c0 + c) * R + r0 + tx * 4) = v;
    }
}

// ---------------------------------------------------------------------------
// 8-way activation blend
// ---------------------------------------------------------------------------
__device__ __forceinline__ float act_blend(float a,
    float w0, float w1, float w2, float w3,
    float w4, float w5, float w6, float w7)
{
    float sig = 1.f / (1.f + expf(-a));
    float elu = (a > 0.f) ? a : (expf(a) - 1.f);
    float th  = tanhf(a);
    float rel = fmaxf(a, 0.f);
    float sil = a * sig;
    float gel = a * 0.5f * (1.f + erff(a * 0.70710678118654752f));
    float sel = (a > 0.f) ? 1.0507009873554805f * a
                          : 1.0507009873554805f * 1.6732632423543772f * (expf(a) - 1.f);
    float sp  = (a > 20.f) ? a : log1pf(expf(a));
    float mish = a * tanhf(sp);
    return w0 * sig + w1 * elu + w2 * th + w3 * rel + w4 * sil + w5 * gel
         + w6 * sel + w7 * mish;
}

// ---------------------------------------------------------------------------
// split-K partial GEMM: P[z][M,NCOL-tile] = A[:,zK..zK+K)*B^T chunk.
// 128x128 tile, S=1, LDS 32KB. XCD-aware swizzle of (bx,by) within z-slice
// (grid x*y must be %8==0 — all uses are). f32 partial out, no epilogue.
// ---------------------------------------------------------------------------
template<int BM, int BN, int NCOL>
__global__ __launch_bounds__(256, 4)
void k_gemm_partial(const u16* __restrict__ A, const u16* __restrict__ B,
                    int Kchunk, int ld, float* __restrict__ P)
{
    constexpr int MT = BM / 32, NT = BN / 32;
    __shared__ __align__(16) u16 smem[2 * (BM + BN) * 32];

    const int nx = gridDim.x, ny = gridDim.y;
    const int f  = blockIdx.x + nx * blockIdx.y;
    const int ch = (nx * ny) >> 3;                 // chunk per XCD
    const int sw = (f & 7) * ch + (f >> 3);        // bijective (nwg%8==0)
    const int bx = sw % nx, by = sw / nx;
    const int row0 = by * BM, col0 = bx * BN;

    const u16* Ac = A + (size_t)blockIdx.z * Kchunk;
    const u16* Bc = B + (size_t)blockIdx.z * Kchunk;

    f32x4 acc[MT][NT];
    gemm_core_db<BM, BN, 1>(Ac, Bc, Kchunk, ld, row0, col0, smem, acc);

    float* Pz = P + (size_t)blockIdx.z * 2048 * NCOL;
    const int tid = threadIdx.x, lane = tid & 63, wv = tid >> 6;
    const int wr = wv >> 1, wc = wv & 1, lr = lane & 15, kg = lane >> 4;
#pragma unroll
    for (int i = 0; i < MT; i++)
#pragma unroll
        for (int r = 0; r < 4; r++) {
            int n = row0 + wr * (BM / 2) + i * 16 + kg * 4 + r;
            size_t ob = (size_t)n * NCOL;
#pragma unroll
            for (int j = 0; j < NT; j++)
                Pz[ob + col0 + wc * (BN / 2) + j * 16 + lr] = acc[i][j][r];
        }
}

// ---------------------------------------------------------------------------
// reduce 4 split-K partials + GEMM-A epilogue:
// blend[n,u] = blend8(relu((sum_s P[s][n,u] + gate[n]·b[u])*conn[u]*mask[u]))
// one block per row n; thread handles 8 consecutive u.
// ---------------------------------------------------------------------------
__global__ __launch_bounds__(256)
void k_reduce_blend(const float* __restrict__ P, const float* __restrict__ gate,
                    const float* __restrict__ conn, const float* __restrict__ mask,
                    const float* __restrict__ wts, const float* __restrict__ bbias,
                    u16* __restrict__ blend)
{
    constexpr size_t SL = (size_t)2048 * 2048;
    const int n  = blockIdx.x;
    const int u0 = threadIdx.x * 8;
    const float* base = P + (size_t)n * 2048 + u0;

    float v[8];
#pragma unroll
    for (int h = 0; h < 2; h++) {
        float4 a = *(const float4*)(base + h * 4);
        float4 b = *(const float4*)(base + SL + h * 4);
        float4 c = *(const float4*)(base + 2 * SL + h * 4);
        float4 d = *(const float4*)(base + 3 * SL + h * 4);
        v[h * 4 + 0] = a.x + b.x + c.x + d.x;
        v[h * 4 + 1] = a.y + b.y + c.y + d.y;
        v[h * 4 + 2] = a.z + b.z + c.z + d.z;
        v[h * 4 + 3] = a.w + b.w + c.w + d.w;
    }
    float4 g = *(const float4*)(gate + n * 4);
    const float w0 = wts[0], w1 = wts[1], w2 = wts[2], w3 = wts[3];
    const float w4 = wts[4], w5 = wts[5], w6 = wts[6], w7 = wts[7];

    ushort4 o[2];
#pragma unroll
    for (int j = 0; j < 8; j++) {
        int u = u0 + j;
        float4 b4 = *(const float4*)(bbias + u * 4);
        float z = v[j] + g.x * b4.x + g.y * b4.y + g.z * b4.z + g.w * b4.w;
        float a = fmaxf(z * conn[u] * mask[u], 0.f);
        u16 r = f2b(act_blend(a, w0, w1, w2, w3, w4, w5, w6, w7));
        ((u16*)o)[j] = r;
    }
    *(ushort4*)(blend + (size_t)n * 2048 + u0)     = o[0];
    *(ushort4*)(blend + (size_t)n * 2048 + u0 + 4) = o[1];
}

// ---------------------------------------------------------------------------
// GEMM-B: logits[n,m] = blend@read_W + read_b (bf16 out; softmaxed in place)
// 128x128, S=1, dbuf -> LDS 32 KB, grid (64,16)=1024 + XCD swizzle
// ---------------------------------------------------------------------------
__global__ __launch_bounds__(256, 2)
void k_gemm_logits(const u16* __restrict__ BL, const u16* __restrict__ RWT,
                   const float* __restrict__ rbias, u16* __restrict__ out)
{
    __shared__ __align__(16) u16 smem[2 * (128 + 128) * 32];
    const int nx = gridDim.x, ny = gridDim.y;
    const int f  = blockIdx.x + nx * blockIdx.y;
    const int ch = (nx * ny) >> 3;
    const int sw = (f & 7) * ch + (f >> 3);
    const int bx = sw % nx, by = sw / nx;

    f32x4 acc[4][4];
    const int row0 = by * 128, col0 = bx * 128;
    gemm_core_db<128, 128, 1>(BL, RWT, 2048, 2048, row0, col0, smem, acc);

    const int tid = threadIdx.x, lane = tid & 63, wv = tid >> 6;
    const int wr = wv >> 1, wc = wv & 1, lr = lane & 15, kg = lane >> 4;
    float rb[4]; int mm[4];
#pragma unroll
    for (int j = 0; j < 4; j++) {
        mm[j] = col0 + wc * 64 + j * 16 + lr;
        rb[j] = rbias[mm[j]];
    }
#pragma unroll
    for (int i = 0; i < 4; i++)
#pragma unroll
        for (int r = 0; r < 4; r++) {
            int n = row0 + wr * 64 + i * 16 + kg * 4 + r;
            size_t ob = (size_t)n * 8192;
#pragma unroll
            for (int j = 0; j < 4; j++)
                out[ob + mm[j]] = f2b(acc[i][j][r] + rb[j]);
        }
}

// ---------------------------------------------------------------------------
// in-place row softmax over 8192 bf16 (one block per row, values in registers)
// ---------------------------------------------------------------------------
__global__ __launch_bounds__(256)
void k_softmax(u16* __restrict__ buf)
{
    __shared__ float red[8];
    const int tid = threadIdx.x, lane = tid & 63, wv = tid >> 6;
    u16* row = buf + (size_t)blockIdx.x * 8192;
    float v[32];
    float mx = -1e30f;
#pragma unroll
    for (int s = 0; s < 8; s++) {
        ushort4 u4 = *(const ushort4*)(row + (s * 256 + tid) * 4);
        float a = b2f(u4.x), b = b2f(u4.y), c = b2f(u4.z), d = b2f(u4.w);
        v[s * 4 + 0] = a; v[s * 4 + 1] = b; v[s * 4 + 2] = c; v[s * 4 + 3] = d;
        mx = fmaxf(mx, fmaxf(fmaxf(a, b), fmaxf(c, d)));
    }
#pragma unroll
    for (int off = 32; off > 0; off >>= 1) mx = fmaxf(mx, __shfl_xor(mx, off));
    if (lane == 0) red[wv] = mx;
    __syncthreads();
    mx = fmaxf(fmaxf(red[0], red[1]), fmaxf(red[2], red[3]));
    float sum = 0.f;
#pragma unroll
    for (int k = 0; k < 32; k++) { v[k] = expf(v[k] - mx); sum += v[k]; }
#pragma unroll
    for (int off = 32; off > 0; off >>= 1) sum += __shfl_xor(sum, off);
    if (lane == 0) red[4 + wv] = sum;
    __syncthreads();
    float inv = 1.f / (red[4] + red[5] + red[6] + red[7]);
#pragma unroll
    for (int s = 0; s < 8; s++) {
        ushort4 o;
        o.x = f2b(v[s * 4 + 0] * inv); o.y = f2b(v[s * 4 + 1] * inv);
        o.z = f2b(v[s * 4 + 2] * inv); o.w = f2b(v[s * 4 + 3] * inv);
        *(ushort4*)(row + (s * 256 + tid) * 4) = o;
    }
}

// ---------------------------------------------------------------------------
// reduce 4 split-K partials into final f32 output (GEMM-C tail)
// ---------------------------------------------------------------------------
__global__ __launch_bounds__(256)
void k_reduce_out(const float* __restrict__ P, float* __restrict__ out)
{
    constexpr size_t SL = (size_t)2048 * 1024;
    size_t i = ((size_t)blockIdx.x * 256 + threadIdx.x) * 4;
    float4 a = *(const float4*)(P + i);
    float4 b = *(const float4*)(P + SL + i);
    float4 c = *(const float4*)(P + 2 * SL + i);
    float4 d = *(const float4*)(P + 3 * SL + i);
    float4 o;
    o.x = a.x + b.x + c.x + d.x;
    o.y = a.y + b.y + c.y + d.y;
    o.z = a.z + b.z + c.z + d.z;
    o.w = a.w + b.w + c.w + d.w;
    *(float4*)(out + i) = o;
}

// sentinel: distinctive output if workspace is too small (absmax ~12345)
__global__ void k_fill(float* out, int n)
{
    int i = blockIdx.x * 256 + threadIdx.x;
    if (i < n) out[i] = 12345.f;
}

// ---------------------------------------------------------------------------
extern "C" void kernel_launch(void* const* d_in, const int* in_sizes, int n_in,
                              void* d_out, int out_size, void* d_ws, size_t ws_size,
                              hipStream_t stream)
{
    const float* x     = (const float*)d_in[0];
    const float* w     = (const float*)d_in[1];
    const float* delay = (const float*)d_in[2];
    const float* bb    = (const float*)d_in[3];
    const float* gW    = (const float*)d_in[4];
    const float* gb    = (const float*)d_in[5];
    const float* na    = (const float*)d_in[6];
    const float* cW1   = (const float*)d_in[7];
    const float* cb1   = (const float*)d_in[8];
    const float* cW2   = (const float*)d_in[9];
    const float* cb2   = (const float*)d_in[10];
    const float* mask  = (const float*)d_in[11];
    const float* actw  = (const float*)d_in[12];
    const float* rW    = (const float*)d_in[13];
    const float* rb    = (const float*)d_in[14];
    const float* mem   = (const float*)d_in[15];
    (void)in_sizes; (void)n_in;

    char* ws = (char*)d_ws;
    size_t off = 0;
    auto alloc = [&](size_t bytes) {
        size_t o = off; off += (bytes + 255) & ~(size_t)255; return o;
    };
    size_t o_wts   = alloc(9 * 4);
    size_t o_gate  = alloc(2048 * 4 * 4);
    size_t o_conn  = alloc(2048 * 4);
    size_t o_y     = alloc((size_t)2048 * 4096 * 2);   // y; later aliased as memT
    size_t o_wmT   = alloc((size_t)2048 * 4096 * 2);
    size_t o_blend = alloc((size_t)2048 * 2048 * 2);
    size_t o_rwT   = alloc((size_t)8192 * 2048 * 2);   // rwT; also split-K partials
    size_t o_log   = alloc((size_t)2048 * 8192 * 2);   // logits; A-partials overflow

    if (off > ws_size) {   // loud, distinguishable failure mode
        k_fill<<<(out_size + 255) / 256, 256, 0, stream>>>((float*)d_out, out_size);
        return;
    }

    float* wts   = (float*)(ws + o_wts);
    float* gate  = (float*)(ws + o_gate);
    float* conn  = (float*)(ws + o_conn);
    u16* y       = (u16*)(ws + o_y);
    u16* wmT     = (u16*)(ws + o_wmT);
    u16* blend   = (u16*)(ws + o_blend);
    u16* rwT     = (u16*)(ws + o_rwT);
    u16* logits  = (u16*)(ws + o_log);
    u16* memT    = y;   // y dead after GEMM-A; same size (16 MB)

    // split-K partial buffers, aliased into lifetime holes:
    //   A-partials: 4 x 2048 x 2048 f32 = 64 MB @ [o_rwT, o_rwT+64MB)
    //     (rwT written AFTER reduce_blend; logits written AFTER that) — no overlap.
    //   C-partials: 4 x 2048 x 1024 f32 = 32 MB @ o_rwT (rwT dead after logits).
    float* pA = (float*)(ws + o_rwT);
    float* pC = (float*)(ws + o_rwT);

    k_small<<<1, 256, 0, stream>>>(na, cW1, cb1, cW2, cb2, actw, conn, wts);
    k_gate_y<<<512, 256, 0, stream>>>(x, gW, gb, gate, y);
    k_wmT<<<dim3(32, 32), 256, 0, stream>>>(w, delay, wmT);

    // GEMM-A: z-partials = y[2048,4096] @ wmT[2048,4096]^T, split-K=4 (K=1024 each)
    k_gemm_partial<128, 128, 2048><<<dim3(16, 16, 4), 256, 0, stream>>>(
        y, wmT, 1024, 4096, pA);
    k_reduce_blend<<<2048, 256, 0, stream>>>(pA, gate, conn, mask, wts, bb, blend);

    k_transpose<<<dim3(128, 32), 256, 0, stream>>>(rW, rwT, 2048, 8192);
    k_gemm_logits<<<dim3(64, 16), 256, 0, stream>>>(blend, rwT, rb, logits);
    k_softmax<<<2048, 256, 0, stream>>>(logits);

    k_transpose<<<dim3(16, 128), 256, 0, stream>>>(mem, memT, 8192, 1024);

    // GEMM-C: out-partials = attn[2048,8192] @ memT[1024,8192]^T, split-K=4 (K=2048)
    k_gemm_partial<128, 128, 1024><<<dim3(8, 16, 4), 256, 0, stream>>>(
        logits, memT, 2048, 8192, pC);
    k_reduce_out<<<2048, 256, 0, stream>>>(pC, (float*)d_out);
}

// Round 3
// 465.803 us; speedup vs baseline: 1.3423x; 1.0408x over previous
//
#include <hip/hip_runtime.h>

// ============================================================================
// PlasticityModelMoE — MI355X (gfx950). Inputs f32, output f32, bf16 MFMA.
// R10: resubmission of R9 (container failed twice — suspected infra flake;
// core re-audited: bounds, alignment, double-buffer race, barrier uniformity
// all verified). 256x256 8-phase schedule (T3+T4 counted-vmcnt, T2 st_16x32
// LDS swizzle, T5 setprio) for GEMM-B (logits) and GEMM-A (split-K=4).
//   - 512 thr (8 waves, 2Mx4N), BK=64, LDS 128 KiB (2 buf x (A 32K + B 32K)).
//   - staging: global_load_lds dwordx4, LINEAR dest + inverse-swizzled SOURCE;
//     reads apply the same involution (rule #21). swz: o ^= ((o>>9)&1)<<5.
//   - 4 phases/K-tile; ONE vmcnt(0) per tile at phase-3 end — waits only on
//     loads issued 3 phases earlier (counted-in-effect, never drains fresh).
// GEMM-C stays on the proven 128^2 split-K core.
// ============================================================================

typedef unsigned short u16;
typedef __attribute__((ext_vector_type(8))) short bf16x8;   // 8 bf16 = 4 VGPRs
typedef __attribute__((ext_vector_type(4))) float f32x4;

__device__ __forceinline__ float b2f(u16 h) {
    union { unsigned u; float f; } v; v.u = ((unsigned)h) << 16; return v.f;
}
__device__ __forceinline__ u16 f2b(float f) {
    union { float f; unsigned u; } v; v.f = f;
    unsigned u = v.u;
    return (u16)((u + 0x7fffu + ((u >> 16) & 1u)) >> 16);   // round-nearest-even
}

// async global->LDS, 16B per lane (wave-uniform base + lane*16 — m97 pattern).
__device__ __forceinline__ void async_copy16(void* lds, const void* g) {
    __builtin_amdgcn_global_load_lds(
        (__attribute__((address_space(1))) void*)(g),
        (__attribute__((address_space(3))) void*)(lds), 16, 0, 0);
}

// st_16x32 swizzle (m201/m204): involution on byte offsets within 16 KB half.
__device__ __forceinline__ int swz(int o) { return o ^ (((o >> 9) & 1) << 5); }

// ---------------------------------------------------------------------------
// 256x256 8-phase GEMM core (T2+T3+T4+T5). C[256,256] = A[256,K]*B[256,K]^T.
// 512 thr / 8 waves as 2(M) x 4(N); per-wave 128x64; acc[8][4] f32x4.
// lds: 128 KiB = 2 bufs x { A: 2x(128x64) halves, B: same } bf16, swizzled.
// Ktiles = K/64 (>=2). ld = row stride of A and B in elements.
// ---------------------------------------------------------------------------
__device__ __forceinline__ void stage_tile256(const u16* __restrict__ src, int ld,
                                              int base0, int k0,
                                              char* ldsbase, int tid)
{
#pragma unroll
    for (int h = 0; h < 2; h++)
#pragma unroll
        for (int it = 0; it < 2; it++) {
            int o = it * 8192 + tid * 16;          // linear LDS byte offset
            int s = swz(o);                        // logical source offset
            int r = s >> 7;                        // row within 128-row half
            int c = (s & 127) >> 1;                // bf16 col (multiple of 8)
            async_copy16(ldsbase + h * 16384 + o,
                         src + (size_t)(base0 + h * 128 + r) * ld + k0 + c);
        }
}

__device__ __forceinline__ void gemm256_core8(const u16* __restrict__ A,
                                              const u16* __restrict__ B,
                                              int Ktiles, int ld,
                                              int row0, int col0,
                                              char* lds, f32x4 (&acc)[8][4])
{
    const int tid  = threadIdx.x;
    const int lane = tid & 63;
    const int wv   = tid >> 6;
    const int wr   = wv >> 2;          // 0..1  (M half)
    const int wc   = wv & 3;           // 0..3  (N quarter)
    const int lr   = lane & 15, kg = lane >> 4;

#pragma unroll
    for (int i = 0; i < 8; i++)
#pragma unroll
        for (int j = 0; j < 4; j++) {
            f32x4 z = {0.f, 0.f, 0.f, 0.f};
            acc[i][j] = z;
        }

    // prologue: stage tile 0 into buf 0
    stage_tile256(A, ld, row0, 0, lds, tid);
    stage_tile256(B, ld, col0, 0, lds + 32768, tid);
    asm volatile("s_waitcnt vmcnt(0)" ::: "memory");
    __builtin_amdgcn_s_barrier();

    bf16x8 af[4][2], bfr[2][2];

    for (int t = 0; t < Ktiles; t++) {
        const int buf = (t & 1) << 16;
        const char* sA = lds + buf + wr * 16384;
        const char* sB = lds + buf + 32768 + ((wc >> 1) * 16384);

        auto rdA = [&](int i, int ks) {
            int off = (i * 16 + lr) * 128 + ks * 64 + kg * 16;
            return *(const bf16x8*)(sA + swz(off));
        };
        auto rdB = [&](int j, int ks) {
            int off = ((wc & 1) * 64 + j * 16 + lr) * 128 + ks * 64 + kg * 16;
            return *(const bf16x8*)(sB + swz(off));
        };

        // ---- phase 0: Q(m0-3, n0-1); burst-stage tile t+1 into buf^1 ----
#pragma unroll
        for (int i = 0; i < 4; i++) { af[i][0] = rdA(i, 0); af[i][1] = rdA(i, 1); }
#pragma unroll
        for (int j = 0; j < 2; j++) { bfr[j][0] = rdB(j, 0); bfr[j][1] = rdB(j, 1); }
        if (t + 1 < Ktiles) {
            char* nb = lds + (((t + 1) & 1) << 16);
            stage_tile256(A, ld, row0, (t + 1) * 64, nb, tid);
            stage_tile256(B, ld, col0, (t + 1) * 64, nb + 32768, tid);
        }
        __builtin_amdgcn_s_barrier();
        __builtin_amdgcn_s_setprio(1);
#pragma unroll
        for (int i = 0; i < 4; i++)
#pragma unroll
            for (int j = 0; j < 2; j++) {
                acc[i][j] = __builtin_amdgcn_mfma_f32_16x16x32_bf16(af[i][0], bfr[j][0], acc[i][j], 0, 0, 0);
                acc[i][j] = __builtin_amdgcn_mfma_f32_16x16x32_bf16(af[i][1], bfr[j][1], acc[i][j], 0, 0, 0);
            }
        __builtin_amdgcn_s_setprio(0);
        __builtin_amdgcn_s_barrier();

        // ---- phase 1: Q(m4-7, n0-1): new A halves ----
#pragma unroll
        for (int i = 0; i < 4; i++) { af[i][0] = rdA(4 + i, 0); af[i][1] = rdA(4 + i, 1); }
        __builtin_amdgcn_s_barrier();
        __builtin_amdgcn_s_setprio(1);
#pragma unroll
        for (int i = 0; i < 4; i++)
#pragma unroll
            for (int j = 0; j < 2; j++) {
                acc[4 + i][j] = __builtin_amdgcn_mfma_f32_16x16x32_bf16(af[i][0], bfr[j][0], acc[4 + i][j], 0, 0, 0);
                acc[4 + i][j] = __builtin_amdgcn_mfma_f32_16x16x32_bf16(af[i][1], bfr[j][1], acc[4 + i][j], 0, 0, 0);
            }
        __builtin_amdgcn_s_setprio(0);
        __builtin_amdgcn_s_barrier();

        // ---- phase 2: Q(m4-7, n2-3): new B ----
#pragma unroll
        for (int j = 0; j < 2; j++) { bfr[j][0] = rdB(2 + j, 0); bfr[j][1] = rdB(2 + j, 1); }
        __builtin_amdgcn_s_barrier();
        __builtin_amdgcn_s_setprio(1);
#pragma unroll
        for (int i = 0; i < 4; i++)
#pragma unroll
            for (int j = 0; j < 2; j++) {
                acc[4 + i][2 + j] = __builtin_amdgcn_mfma_f32_16x16x32_bf16(af[i][0], bfr[j][0], acc[4 + i][2 + j], 0, 0, 0);
                acc[4 + i][2 + j] = __builtin_amdgcn_mfma_f32_16x16x32_bf16(af[i][1], bfr[j][1], acc[4 + i][2 + j], 0, 0, 0);
            }
        __builtin_amdgcn_s_setprio(0);
        __builtin_amdgcn_s_barrier();

        // ---- phase 3: Q(m0-3, n2-3): reload A m0-3; tile-boundary vmcnt ----
#pragma unroll
        for (int i = 0; i < 4; i++) { af[i][0] = rdA(i, 0); af[i][1] = rdA(i, 1); }
        __builtin_amdgcn_s_barrier();
        __builtin_amdgcn_s_setprio(1);
#pragma unroll
        for (int i = 0; i < 4; i++)
#pragma unroll
            for (int j = 0; j < 2; j++) {
                acc[i][2 + j] = __builtin_amdgcn_mfma_f32_16x16x32_bf16(af[i][0], bfr[j][0], acc[i][2 + j], 0, 0, 0);
                acc[i][2 + j] = __builtin_amdgcn_mfma_f32_16x16x32_bf16(af[i][1], bfr[j][1], acc[i][2 + j], 0, 0, 0);
            }
        __builtin_amdgcn_s_setprio(0);
        // loads for tile t+1 were issued 3 phases ago — wait them, then sync
        asm volatile("s_waitcnt vmcnt(0)" ::: "memory");
        __builtin_amdgcn_s_barrier();
    }
}

// ---------------------------------------------------------------------------
// Double-buffered 2-phase GEMM core (proven) — still used by GEMM-C.
// ---------------------------------------------------------------------------
template<int BM, int BN, int S>
__device__ __forceinline__ void gemm_core_db(const u16* __restrict__ A,
                                             const u16* __restrict__ B,
                                             int Kloop, int ld,
                                             int row0, int col0,
                                             u16* smem,
                                             f32x4 (&acc)[BM / 32][BN / 32])
{
    constexpr int MT = BM / 32, NT = BN / 32;
    constexpr int STG = (BM + BN) * 32;     // u16 per stage
    constexpr int SET = STG * S;            // u16 per buffer set
    const int tid  = threadIdx.x;
    const int lane = tid & 63;
    const int wv   = tid >> 6;
    const int wr   = wv >> 1, wc = wv & 1;
    const int lr   = lane & 15, kg = lane >> 4;

#pragma unroll
    for (int i = 0; i < MT; i++)
#pragma unroll
        for (int j = 0; j < NT; j++) {
            f32x4 z = {0.f, 0.f, 0.f, 0.f};
            acc[i][j] = z;
        }

    auto stage_in = [&](u16* set, int k0) {
#pragma unroll
        for (int c = tid; c < BM * 4; c += 256) {
            const u16* gA = A + (size_t)(row0 + (c >> 2)) * ld + k0 + (c & 3) * 8;
#pragma unroll
            for (int s = 0; s < S; s++)
                async_copy16(set + s * STG + c * 8, gA + s * 32);
        }
#pragma unroll
        for (int c = tid; c < BN * 4; c += 256) {
            const u16* gB = B + (size_t)(col0 + (c >> 2)) * ld + k0 + (c & 3) * 8;
#pragma unroll
            for (int s = 0; s < S; s++)
                async_copy16(set + s * STG + BM * 32 + c * 8, gB + s * 32);
        }
    };

    stage_in(smem, 0);
    __syncthreads();           // drain prologue staging

    int p = 0;
    for (int k0 = 0; k0 < Kloop; k0 += 32 * S) {
        if (k0 + 32 * S < Kloop)
            stage_in(smem + (p ^ 1) * SET, k0 + 32 * S);   // prefetch next window
        u16* set = smem + p * SET;
#pragma unroll
        for (int s = 0; s < S; s++) {
            const u16* sA = set + s * STG;
            const u16* sB = sA + BM * 32;
            bf16x8 af[MT], bfr[NT];
#pragma unroll
            for (int i = 0; i < MT; i++)
                af[i] = *(const bf16x8*)(sA + ((wr * (BM / 2) + i * 16 + lr) * 32 + kg * 8));
#pragma unroll
            for (int j = 0; j < NT; j++)
                bfr[j] = *(const bf16x8*)(sB + ((wc * (BN / 2) + j * 16 + lr) * 32 + kg * 8));
#pragma unroll
            for (int i = 0; i < MT; i++)
#pragma unroll
                for (int j = 0; j < NT; j++)
                    acc[i][j] = __builtin_amdgcn_mfma_f32_16x16x32_bf16(
                                    af[i], bfr[j], acc[i][j], 0, 0, 0);
        }
        __syncthreads();       // one barrier/window; vmcnt drain overlapped above
        p ^= 1;
    }
}

// ---------------------------------------------------------------------------
// tiny: conn = sigmoid(relu(na@W1+b1)@W2+b2), wts = softmax(act_w). All f32.
// ---------------------------------------------------------------------------
__global__ __launch_bounds__(256)
void k_small(const float* __restrict__ na, const float* __restrict__ W1,
             const float* __restrict__ b1, const float* __restrict__ W2,
             const float* __restrict__ b2, const float* __restrict__ actw,
             float* __restrict__ conn, float* __restrict__ wts)
{
    __shared__ float red[256 * 32];
    __shared__ float hsh[32];
    const int tid = threadIdx.x;
    float h[32];
#pragma unroll
    for (int k = 0; k < 32; k++) h[k] = 0.f;
    for (int u = tid; u < 2048; u += 256) {
        float nav = na[u];
        const float* row = W1 + u * 32;
#pragma unroll
        for (int k = 0; k < 32; k++) h[k] += nav * row[k];
    }
#pragma unroll
    for (int k = 0; k < 32; k++) red[tid * 32 + k] = h[k];
    for (int s = 128; s > 0; s >>= 1) {
        __syncthreads();
        if (tid < s)
#pragma unroll
            for (int k = 0; k < 32; k++) red[tid * 32 + k] += red[(tid + s) * 32 + k];
    }
    __syncthreads();
    if (tid < 32) hsh[tid] = fmaxf(red[tid] + b1[tid], 0.f);
    if (tid == 0) {
        float e[9], m = -1e30f;
        for (int i = 0; i < 9; i++) { e[i] = actw[i]; m = fmaxf(m, e[i]); }
        float s = 0.f;
        for (int i = 0; i < 9; i++) { e[i] = expf(e[i] - m); s += e[i]; }
        for (int i = 0; i < 9; i++) wts[i] = e[i] / s;
    }
    __syncthreads();
    for (int u = tid; u < 2048; u += 256) {
        float a = 0.f;
#pragma unroll
        for (int k = 0; k < 32; k++) a += hsh[k] * W2[k * 2048 + u];
        conn[u] = 1.f / (1.f + expf(-(a + b2[u])));
    }
}

// ---------------------------------------------------------------------------
// gate softmax + y = x*gate (bf16 out). One wave per row n.
// ---------------------------------------------------------------------------
__global__ __launch_bounds__(256)
void k_gate_y(const float* __restrict__ x, const float* __restrict__ gW,
              const float* __restrict__ gb, float* __restrict__ gate,
              u16* __restrict__ y)
{
    const int tid = threadIdx.x, lane = tid & 63, wv = tid >> 6;
    const int n = blockIdx.x * 4 + wv;
    const float* xr = x + (size_t)n * 1024;
    float a0 = 0, a1 = 0, a2 = 0, a3 = 0;
    float xv[16];
#pragma unroll
    for (int s = 0; s < 16; s++) {
        int d = s * 64 + lane;
        float xd = xr[d]; xv[s] = xd;
        float4 g4 = *(const float4*)(gW + d * 4);
        a0 += xd * g4.x; a1 += xd * g4.y; a2 += xd * g4.z; a3 += xd * g4.w;
    }
#pragma unroll
    for (int off = 32; off > 0; off >>= 1) {
        a0 += __shfl_xor(a0, off); a1 += __shfl_xor(a1, off);
        a2 += __shfl_xor(a2, off); a3 += __shfl_xor(a3, off);
    }
    a0 += gb[0]; a1 += gb[1]; a2 += gb[2]; a3 += gb[3];
    float m = fmaxf(fmaxf(a0, a1), fmaxf(a2, a3));
    float e0 = expf(a0 - m), e1 = expf(a1 - m), e2 = expf(a2 - m), e3 = expf(a3 - m);
    float inv = 1.f / (e0 + e1 + e2 + e3);
    float g0 = e0 * inv, g1 = e1 * inv, g2 = e2 * inv, g3 = e3 * inv;
    if (lane == 0) *(float4*)(gate + n * 4) = make_float4(g0, g1, g2, g3);
#pragma unroll
    for (int s = 0; s < 16; s++) {
        int d = s * 64 + lane;
        ushort4 o;
        o.x = f2b(xv[s] * g0); o.y = f2b(xv[s] * g1);
        o.z = f2b(xv[s] * g2); o.w = f2b(xv[s] * g3);
        *(ushort4*)(y + (size_t)n * 4096 + d * 4) = o;
    }
}

// ---------------------------------------------------------------------------
// wmT[u, d*4+b] = w[d,u,b] * sigmoid(delay[d,u,b]); f32 in, bf16 out.
// ---------------------------------------------------------------------------
__global__ __launch_bounds__(256)
void k_wmT(const float* __restrict__ w, const float* __restrict__ delay,
           u16* __restrict__ wmT)
{
    __shared__ __align__(16) ushort4 tile[32][65];
    const int tid = threadIdx.x;
    const int tx = tid & 63, ty = tid >> 6;          // tx: u, ty: d-subset
    const int u0 = blockIdx.x * 64, d0 = blockIdx.y * 32;
#pragma unroll
    for (int i = 0; i < 8; i++) {
        int d = i * 4 + ty;
        size_t idx = ((size_t)(d0 + d) * 2048 + (u0 + tx)) * 4;
        float4 w4 = *(const float4*)(w + idx);
        float4 d4 = *(const float4*)(delay + idx);
        ushort4 o;
        o.x = f2b(w4.x / (1.f + expf(-d4.x)));
        o.y = f2b(w4.y / (1.f + expf(-d4.y)));
        o.z = f2b(w4.z / (1.f + expf(-d4.z)));
        o.w = f2b(w4.w / (1.f + expf(-d4.w)));
        tile[d][tx] = o;
    }
    __syncthreads();
    const int dx = tid & 31, uy = tid >> 5;
#pragma unroll
    for (int i = 0; i < 8; i++) {
        int u = i * 8 + uy;
        *(ushort4*)(wmT + (size_t)(u0 + u) * 4096 + (d0 + dx) * 4) = tile[dx][u];
    }
}

// ---------------------------------------------------------------------------
// transpose + cast: in[R,C] f32 -> out[C,R] bf16, 64x64 tiles
// ---------------------------------------------------------------------------
__global__ __launch_bounds__(256)
void k_transpose(const float* __restrict__ in, u16* __restrict__ out, int R, int C)
{
    __shared__ __align__(16) u16 t[64][68];
    const int tid = threadIdx.x, tx = tid & 15, ty = tid >> 4;
    const int c0 = blockIdx.x * 64, r0 = blockIdx.y * 64;
#pragma unroll
    for (int i = 0; i < 4; i++) {
        int r = r0 + ty + i * 16;
        float4 v = *(const float4*)(in + (size_t)r * C + c0 + tx * 4);
        t[tx * 4 + 0][ty + i * 16] = f2b(v.x); t[tx * 4 + 1][ty + i * 16] = f2b(v.y);
        t[tx * 4 + 2][ty + i * 16] = f2b(v.z); t[tx * 4 + 3][ty + i * 16] = f2b(v.w);
    }
    __syncthreads();
#pragma unroll
    for (int i = 0; i < 4; i++) {
        int c = ty + i * 16;
        ushort4 v;
        v.x = t[c][tx * 4 + 0]; v.y = t[c][tx * 4 + 1];
        v.z = t[c][tx * 4 + 2]; v.w = t[c][tx * 4 + 3];
        *(ushort4*)(out + (size_t)(c0 + c) * R + r0 + tx * 4) = v;
    }
}

// ---------------------------------------------------------------------------
// 8-way activation blend
// ---------------------------------------------------------------------------
__device__ __forceinline__ float act_blend(float a,
    float w0, float w1, float w2, float w3,
    float w4, float w5, float w6, float w7)
{
    float sig = 1.f / (1.f + expf(-a));
    float elu = (a > 0.f) ? a : (expf(a) - 1.f);
    float th  = tanhf(a);
    float rel = fmaxf(a, 0.f);
    float sil = a * sig;
    float gel = a * 0.5f * (1.f + erff(a * 0.70710678118654752f));
    float sel = (a > 0.f) ? 1.0507009873554805f * a
                          : 1.0507009873554805f * 1.6732632423543772f * (expf(a) - 1.f);
    float sp  = (a > 20.f) ? a : log1pf(expf(a));
    float mish = a * tanhf(sp);
    return w0 * sig + w1 * elu + w2 * th + w3 * rel + w4 * sil + w5 * gel
         + w6 * sel + w7 * mish;
}

// ---------------------------------------------------------------------------
// GEMM-A (8-phase 256^2, split-K): P[z][n,u] partial = y@wmT^T over K-chunk z.
// grid (8, 8, 4), 512 thr, LDS 128 KiB -> 256 blocks, 1/CU.
// ---------------------------------------------------------------------------
__global__ __launch_bounds__(512, 2)
void k_gemm_a8(const u16* __restrict__ A, const u16* __restrict__ B,
               float* __restrict__ P)
{
    __shared__ __align__(16) char lds[131072];
    const int row0 = blockIdx.y * 256, col0 = blockIdx.x * 256;
    const u16* Ac = A + (size_t)blockIdx.z * 1024;
    const u16* Bc = B + (size_t)blockIdx.z * 1024;

    f32x4 acc[8][4];
    gemm256_core8(Ac, Bc, 16, 4096, row0, col0, lds, acc);

    float* Pz = P + (size_t)blockIdx.z * 2048 * 2048;
    const int tid = threadIdx.x, lane = tid & 63, wv = tid >> 6;
    const int wr = wv >> 2, wc = wv & 3, lr = lane & 15, kg = lane >> 4;
#pragma unroll
    for (int i = 0; i < 8; i++)
#pragma unroll
        for (int r = 0; r < 4; r++) {
            int n = row0 + wr * 128 + i * 16 + kg * 4 + r;
            size_t ob = (size_t)n * 2048;
#pragma unroll
            for (int j = 0; j < 4; j++)
                Pz[ob + col0 + wc * 64 + j * 16 + lr] = acc[i][j][r];
        }
}

// ---------------------------------------------------------------------------
// reduce 4 split-K partials + GEMM-A epilogue:
// blend[n,u] = blend8(relu((sum_s P[s][n,u] + gate[n]·b[u])*conn[u]*mask[u]))
// ---------------------------------------------------------------------------
__global__ __launch_bounds__(256)
void k_reduce_blend(const float* __restrict__ P, const float* __restrict__ gate,
                    const float* __restrict__ conn, const float* __restrict__ mask,
                    const float* __restrict__ wts, const float* __restrict__ bbias,
                    u16* __restrict__ blend)
{
    constexpr size_t SL = (size_t)2048 * 2048;
    const int n  = blockIdx.x;
    const int u0 = threadIdx.x * 8;
    const float* base = P + (size_t)n * 2048 + u0;

    float v[8];
#pragma unroll
    for (int h = 0; h < 2; h++) {
        float4 a = *(const float4*)(base + h * 4);
        float4 b = *(const float4*)(base + SL + h * 4);
        float4 c = *(const float4*)(base + 2 * SL + h * 4);
        float4 d = *(const float4*)(base + 3 * SL + h * 4);
        v[h * 4 + 0] = a.x + b.x + c.x + d.x;
        v[h * 4 + 1] = a.y + b.y + c.y + d.y;
        v[h * 4 + 2] = a.z + b.z + c.z + d.z;
        v[h * 4 + 3] = a.w + b.w + c.w + d.w;
    }
    float4 g = *(const float4*)(gate + n * 4);
    const float w0 = wts[0], w1 = wts[1], w2 = wts[2], w3 = wts[3];
    const float w4 = wts[4], w5 = wts[5], w6 = wts[6], w7 = wts[7];

    ushort4 o[2];
#pragma unroll
    for (int j = 0; j < 8; j++) {
        int u = u0 + j;
        float4 b4 = *(const float4*)(bbias + u * 4);
        float z = v[j] + g.x * b4.x + g.y * b4.y + g.z * b4.z + g.w * b4.w;
        float a = fmaxf(z * conn[u] * mask[u], 0.f);
        u16 r = f2b(act_blend(a, w0, w1, w2, w3, w4, w5, w6, w7));
        ((u16*)o)[j] = r;
    }
    *(ushort4*)(blend + (size_t)n * 2048 + u0)     = o[0];
    *(ushort4*)(blend + (size_t)n * 2048 + u0 + 4) = o[1];
}

// ---------------------------------------------------------------------------
// GEMM-B (8-phase 256^2): logits[n,m] = blend@read_W^T + read_b (bf16 out)
// grid (32, 8), 512 thr -> 256 blocks, 1/CU.
// ---------------------------------------------------------------------------
__global__ __launch_bounds__(512, 2)
void k_gemm_logits8(const u16* __restrict__ BL, const u16* __restrict__ RWT,
                    const float* __restrict__ rbias, u16* __restrict__ out)
{
    __shared__ __align__(16) char lds[131072];
    const int row0 = blockIdx.y * 256, col0 = blockIdx.x * 256;

    f32x4 acc[8][4];
    gemm256_core8(BL, RWT, 32, 2048, row0, col0, lds, acc);

    const int tid = threadIdx.x, lane = tid & 63, wv = tid >> 6;
    const int wr = wv >> 2, wc = wv & 3, lr = lane & 15, kg = lane >> 4;
    float rb[4]; int mm[4];
#pragma unroll
    for (int j = 0; j < 4; j++) {
        mm[j] = col0 + wc * 64 + j * 16 + lr;
        rb[j] = rbias[mm[j]];
    }
#pragma unroll
    for (int i = 0; i < 8; i++)
#pragma unroll
        for (int r = 0; r < 4; r++) {
            int n = row0 + wr * 128 + i * 16 + kg * 4 + r;
            size_t ob = (size_t)n * 8192;
#pragma unroll
            for (int j = 0; j < 4; j++)
                out[ob + mm[j]] = f2b(acc[i][j][r] + rb[j]);
        }
}

// ---------------------------------------------------------------------------
// in-place row softmax over 8192 bf16 (one block per row, values in registers)
// ---------------------------------------------------------------------------
__global__ __launch_bounds__(256)
void k_softmax(u16* __restrict__ buf)
{
    __shared__ float red[8];
    const int tid = threadIdx.x, lane = tid & 63, wv = tid >> 6;
    u16* row = buf + (size_t)blockIdx.x * 8192;
    float v[32];
    float mx = -1e30f;
#pragma unroll
    for (int s = 0; s < 8; s++) {
        ushort4 u4 = *(const ushort4*)(row + (s * 256 + tid) * 4);
        float a = b2f(u4.x), b = b2f(u4.y), c = b2f(u4.z), d = b2f(u4.w);
        v[s * 4 + 0] = a; v[s * 4 + 1] = b; v[s * 4 + 2] = c; v[s * 4 + 3] = d;
        mx = fmaxf(mx, fmaxf(fmaxf(a, b), fmaxf(c, d)));
    }
#pragma unroll
    for (int off = 32; off > 0; off >>= 1) mx = fmaxf(mx, __shfl_xor(mx, off));
    if (lane == 0) red[wv] = mx;
    __syncthreads();
    mx = fmaxf(fmaxf(red[0], red[1]), fmaxf(red[2], red[3]));
    float sum = 0.f;
#pragma unroll
    for (int k = 0; k < 32; k++) { v[k] = expf(v[k] - mx); sum += v[k]; }
#pragma unroll
    for (int off = 32; off > 0; off >>= 1) sum += __shfl_xor(sum, off);
    if (lane == 0) red[4 + wv] = sum;
    __syncthreads();
    float inv = 1.f / (red[4] + red[5] + red[6] + red[7]);
#pragma unroll
    for (int s = 0; s < 8; s++) {
        ushort4 o;
        o.x = f2b(v[s * 4 + 0] * inv); o.y = f2b(v[s * 4 + 1] * inv);
        o.z = f2b(v[s * 4 + 2] * inv); o.w = f2b(v[s * 4 + 3] * inv);
        *(ushort4*)(row + (s * 256 + tid) * 4) = o;
    }
}

// ---------------------------------------------------------------------------
// GEMM-C (proven 128^2 split-K): P[z][n,md] partial = attn @ memory chunk.
// ---------------------------------------------------------------------------
template<int BM, int BN, int NCOL>
__global__ __launch_bounds__(256, 4)
void k_gemm_partial(const u16* __restrict__ A, const u16* __restrict__ B,
                    int Kchunk, int ld, float* __restrict__ P)
{
    constexpr int MT = BM / 32, NT = BN / 32;
    __shared__ __align__(16) u16 smem[2 * (BM + BN) * 32];

    const int nx = gridDim.x, ny = gridDim.y;
    const int f  = blockIdx.x + nx * blockIdx.y;
    const int ch = (nx * ny) >> 3;                 // chunk per XCD
    const int sw = (f & 7) * ch + (f >> 3);        // bijective (nwg%8==0)
    const int bx = sw % nx, by = sw / nx;
    const int row0 = by * BM, col0 = bx * BN;

    const u16* Ac = A + (size_t)blockIdx.z * Kchunk;
    const u16* Bc = B + (size_t)blockIdx.z * Kchunk;

    f32x4 acc[MT][NT];
    gemm_core_db<BM, BN, 1>(Ac, Bc, Kchunk, ld, row0, col0, smem, acc);

    float* Pz = P + (size_t)blockIdx.z * 2048 * NCOL;
    const int tid = threadIdx.x, lane = tid & 63, wv = tid >> 6;
    const int wr = wv >> 1, wc = wv & 1, lr = lane & 15, kg = lane >> 4;
#pragma unroll
    for (int i = 0; i < MT; i++)
#pragma unroll
        for (int r = 0; r < 4; r++) {
            int n = row0 + wr * (BM / 2) + i * 16 + kg * 4 + r;
            size_t ob = (size_t)n * NCOL;
#pragma unroll
            for (int j = 0; j < NT; j++)
                Pz[ob + col0 + wc * (BN / 2) + j * 16 + lr] = acc[i][j][r];
        }
}

// ---------------------------------------------------------------------------
// reduce 4 split-K partials into final f32 output (GEMM-C tail)
// ---------------------------------------------------------------------------
__global__ __launch_bounds__(256)
void k_reduce_out(const float* __restrict__ P, float* __restrict__ out)
{
    constexpr size_t SL = (size_t)2048 * 1024;
    size_t i = ((size_t)blockIdx.x * 256 + threadIdx.x) * 4;
    float4 a = *(const float4*)(P + i);
    float4 b = *(const float4*)(P + SL + i);
    float4 c = *(const float4*)(P + 2 * SL + i);
    float4 d = *(const float4*)(P + 3 * SL + i);
    float4 o;
    o.x = a.x + b.x + c.x + d.x;
    o.y = a.y + b.y + c.y + d.y;
    o.z = a.z + b.z + c.z + d.z;
    o.w = a.w + b.w + c.w + d.w;
    *(float4*)(out + i) = o;
}

// sentinel: distinctive output if workspace is too small (absmax ~12345)
__global__ void k_fill(float* out, int n)
{
    int i = blockIdx.x * 256 + threadIdx.x;
    if (i < n) out[i] = 12345.f;
}

// ---------------------------------------------------------------------------
extern "C" void kernel_launch(void* const* d_in, const int* in_sizes, int n_in,
                              void* d_out, int out_size, void* d_ws, size_t ws_size,
                              hipStream_t stream)
{
    const float* x     = (const float*)d_in[0];
    const float* w     = (const float*)d_in[1];
    const float* delay = (const float*)d_in[2];
    const float* bb    = (const float*)d_in[3];
    const float* gW    = (const float*)d_in[4];
    const float* gb    = (const float*)d_in[5];
    const float* na    = (const float*)d_in[6];
    const float* cW1   = (const float*)d_in[7];
    const float* cb1   = (const float*)d_in[8];
    const float* cW2   = (const float*)d_in[9];
    const float* cb2   = (const float*)d_in[10];
    const float* mask  = (const float*)d_in[11];
    const float* actw  = (const float*)d_in[12];
    const float* rW    = (const float*)d_in[13];
    const float* rb    = (const float*)d_in[14];
    const float* mem   = (const float*)d_in[15];
    (void)in_sizes; (void)n_in;

    char* ws = (char*)d_ws;
    size_t off = 0;
    auto alloc = [&](size_t bytes) {
        size_t o = off; off += (bytes + 255) & ~(size_t)255; return o;
    };
    size_t o_wts   = alloc(9 * 4);
    size_t o_gate  = alloc(2048 * 4 * 4);
    size_t o_conn  = alloc(2048 * 4);
    size_t o_y     = alloc((size_t)2048 * 4096 * 2);   // y; later aliased as memT
    size_t o_wmT   = alloc((size_t)2048 * 4096 * 2);
    size_t o_blend = alloc((size_t)2048 * 2048 * 2);
    size_t o_rwT   = alloc((size_t)8192 * 2048 * 2);   // rwT; also split-K partials
    size_t o_log   = alloc((size_t)2048 * 8192 * 2);   // logits; A-partials overflow

    if (off > ws_size) {   // loud, distinguishable failure mode
        k_fill<<<(out_size + 255) / 256, 256, 0, stream>>>((float*)d_out, out_size);
        return;
    }

    float* wts   = (float*)(ws + o_wts);
    float* gate  = (float*)(ws + o_gate);
    float* conn  = (float*)(ws + o_conn);
    u16* y       = (u16*)(ws + o_y);
    u16* wmT     = (u16*)(ws + o_wmT);
    u16* blend   = (u16*)(ws + o_blend);
    u16* rwT     = (u16*)(ws + o_rwT);
    u16* logits  = (u16*)(ws + o_log);
    u16* memT    = y;   // y dead after GEMM-A; same size (16 MB)

    // split-K partial buffers, aliased into lifetime holes:
    //   A-partials: 4 x 2048 x 2048 f32 = 64 MB @ [o_rwT, o_rwT+64MB)
    //     (rwT written AFTER reduce_blend; logits written AFTER that) — no overlap.
    //   C-partials: 4 x 2048 x 1024 f32 = 32 MB @ o_rwT (rwT dead after logits).
    float* pA = (float*)(ws + o_rwT);
    float* pC = (float*)(ws + o_rwT);

    k_small<<<1, 256, 0, stream>>>(na, cW1, cb1, cW2, cb2, actw, conn, wts);
    k_gate_y<<<512, 256, 0, stream>>>(x, gW, gb, gate, y);
    k_wmT<<<dim3(32, 32), 256, 0, stream>>>(w, delay, wmT);

    // GEMM-A: partials = y[2048,4096] @ wmT[2048,4096]^T, split-K=4 (K=1024 each)
    k_gemm_a8<<<dim3(8, 8, 4), 512, 0, stream>>>(y, wmT, pA);
    k_reduce_blend<<<2048, 256, 0, stream>>>(pA, gate, conn, mask, wts, bb, blend);

    k_transpose<<<dim3(128, 32), 256, 0, stream>>>(rW, rwT, 2048, 8192);
    k_gemm_logits8<<<dim3(32, 8), 512, 0, stream>>>(blend, rwT, rb, logits);
    k_softmax<<<2048, 256, 0, stream>>>(logits);

    k_transpose<<<dim3(16, 128), 256, 0, stream>>>(mem, memT, 8192, 1024);

    // GEMM-C: out-partials = attn[2048,8192] @ memT[1024,8192]^T, split-K=4 (K=2048)
    k_gemm_partial<128, 128, 1024><<<dim3(8, 16, 4), 256, 0, stream>>>(
        logits, memT, 2048, 8192, pC);
    k_reduce_out<<<2048, 256, 0, stream>>>(pC, (float*)d_out);
}

// Round 4
// 453.458 us; speedup vs baseline: 1.3789x; 1.0272x over previous
//
#include <hip/hip_runtime.h>

// ============================================================================
// PlasticityModelMoE — MI355X (gfx950). Inputs f32, output f32, bf16 MFMA.
// R11: fix the LDS swizzle. R10's 1-bit st_16x32 XOR left an 8-way conflict
// (BANK_CONFLICT stayed 8.39M = 4 cyc/ds_read_b128): with 128B rows, a
// 16-lane quarter reads 16 rows at the SAME 16B slot; slot bits are [6:4],
// row bits [9:7], so the conflict-free involution is the FULL 3-bit XOR
//   swz(o) = o ^ (((o>>7)&7)<<4)        (slot ^= row&7)
// -> each quarter covers 8 slots x 2 lanes = 2-way = free (m136).
// Same logic for the 2-phase core (64B rows): bits[5:4] ^= bits[7:6]
// (8-way -> 4-way, best within-row). Both sides (stage source + reads)
// swizzled per rule #21. No structural changes vs R10.
// ============================================================================

typedef unsigned short u16;
typedef __attribute__((ext_vector_type(8))) short bf16x8;   // 8 bf16 = 4 VGPRs
typedef __attribute__((ext_vector_type(4))) float f32x4;

__device__ __forceinline__ float b2f(u16 h) {
    union { unsigned u; float f; } v; v.u = ((unsigned)h) << 16; return v.f;
}
__device__ __forceinline__ u16 f2b(float f) {
    union { float f; unsigned u; } v; v.f = f;
    unsigned u = v.u;
    return (u16)((u + 0x7fffu + ((u >> 16) & 1u)) >> 16);   // round-nearest-even
}

// async global->LDS, 16B per lane (wave-uniform base + lane*16 — m97 pattern).
__device__ __forceinline__ void async_copy16(void* lds, const void* g) {
    __builtin_amdgcn_global_load_lds(
        (__attribute__((address_space(1))) void*)(g),
        (__attribute__((address_space(3))) void*)(lds), 16, 0, 0);
}

// 3-bit swizzle for 128B-row tiles: 16B-slot bits [6:4] ^= row bits [9:7].
// Involution; stays within its 128B row; spreads 8 consecutive rows across
// all 8 slots -> ds_read_b128 quarters hit 2 lanes/slot (free).
__device__ __forceinline__ int swz(int o) { return o ^ (((o >> 7) & 7) << 4); }

// 2-bit swizzle for 64B-row tiles (2-phase core): slot bits [5:4] ^= row
// bits [7:6]. 8-way -> 4-way.
__device__ __forceinline__ int swz64(int kg, int row) { return kg ^ (row & 3); }

// ---------------------------------------------------------------------------
// 256x256 8-phase GEMM core (T2+T3+T4+T5). C[256,256] = A[256,K]*B[256,K]^T.
// 512 thr / 8 waves as 2(M) x 4(N); per-wave 128x64; acc[8][4] f32x4.
// lds: 128 KiB = 2 bufs x { A: 2x(128x64) halves, B: same } bf16, swizzled.
// Ktiles = K/64 (>=2). ld = row stride of A and B in elements.
// ---------------------------------------------------------------------------
__device__ __forceinline__ void stage_tile256(const u16* __restrict__ src, int ld,
                                              int base0, int k0,
                                              char* ldsbase, int tid)
{
#pragma unroll
    for (int h = 0; h < 2; h++)
#pragma unroll
        for (int it = 0; it < 2; it++) {
            int o = it * 8192 + tid * 16;          // linear LDS byte offset
            int s = swz(o);                        // logical source offset
            int r = s >> 7;                        // row within 128-row half
            int c = (s & 127) >> 1;                // bf16 col (multiple of 8)
            async_copy16(ldsbase + h * 16384 + o,
                         src + (size_t)(base0 + h * 128 + r) * ld + k0 + c);
        }
}

__device__ __forceinline__ void gemm256_core8(const u16* __restrict__ A,
                                              const u16* __restrict__ B,
                                              int Ktiles, int ld,
                                              int row0, int col0,
                                              char* lds, f32x4 (&acc)[8][4])
{
    const int tid  = threadIdx.x;
    const int lane = tid & 63;
    const int wv   = tid >> 6;
    const int wr   = wv >> 2;          // 0..1  (M half)
    const int wc   = wv & 3;           // 0..3  (N quarter)
    const int lr   = lane & 15, kg = lane >> 4;

#pragma unroll
    for (int i = 0; i < 8; i++)
#pragma unroll
        for (int j = 0; j < 4; j++) {
            f32x4 z = {0.f, 0.f, 0.f, 0.f};
            acc[i][j] = z;
        }

    // prologue: stage tile 0 into buf 0
    stage_tile256(A, ld, row0, 0, lds, tid);
    stage_tile256(B, ld, col0, 0, lds + 32768, tid);
    asm volatile("s_waitcnt vmcnt(0)" ::: "memory");
    __builtin_amdgcn_s_barrier();

    bf16x8 af[4][2], bfr[2][2];

    for (int t = 0; t < Ktiles; t++) {
        const int buf = (t & 1) << 16;
        const char* sA = lds + buf + wr * 16384;
        const char* sB = lds + buf + 32768 + ((wc >> 1) * 16384);

        auto rdA = [&](int i, int ks) {
            int off = (i * 16 + lr) * 128 + ks * 64 + kg * 16;
            return *(const bf16x8*)(sA + swz(off));
        };
        auto rdB = [&](int j, int ks) {
            int off = ((wc & 1) * 64 + j * 16 + lr) * 128 + ks * 64 + kg * 16;
            return *(const bf16x8*)(sB + swz(off));
        };

        // ---- phase 0: Q(m0-3, n0-1); burst-stage tile t+1 into buf^1 ----
#pragma unroll
        for (int i = 0; i < 4; i++) { af[i][0] = rdA(i, 0); af[i][1] = rdA(i, 1); }
#pragma unroll
        for (int j = 0; j < 2; j++) { bfr[j][0] = rdB(j, 0); bfr[j][1] = rdB(j, 1); }
        if (t + 1 < Ktiles) {
            char* nb = lds + (((t + 1) & 1) << 16);
            stage_tile256(A, ld, row0, (t + 1) * 64, nb, tid);
            stage_tile256(B, ld, col0, (t + 1) * 64, nb + 32768, tid);
        }
        __builtin_amdgcn_s_barrier();
        __builtin_amdgcn_s_setprio(1);
#pragma unroll
        for (int i = 0; i < 4; i++)
#pragma unroll
            for (int j = 0; j < 2; j++) {
                acc[i][j] = __builtin_amdgcn_mfma_f32_16x16x32_bf16(af[i][0], bfr[j][0], acc[i][j], 0, 0, 0);
                acc[i][j] = __builtin_amdgcn_mfma_f32_16x16x32_bf16(af[i][1], bfr[j][1], acc[i][j], 0, 0, 0);
            }
        __builtin_amdgcn_s_setprio(0);
        __builtin_amdgcn_s_barrier();

        // ---- phase 1: Q(m4-7, n0-1): new A halves ----
#pragma unroll
        for (int i = 0; i < 4; i++) { af[i][0] = rdA(4 + i, 0); af[i][1] = rdA(4 + i, 1); }
        __builtin_amdgcn_s_barrier();
        __builtin_amdgcn_s_setprio(1);
#pragma unroll
        for (int i = 0; i < 4; i++)
#pragma unroll
            for (int j = 0; j < 2; j++) {
                acc[4 + i][j] = __builtin_amdgcn_mfma_f32_16x16x32_bf16(af[i][0], bfr[j][0], acc[4 + i][j], 0, 0, 0);
                acc[4 + i][j] = __builtin_amdgcn_mfma_f32_16x16x32_bf16(af[i][1], bfr[j][1], acc[4 + i][j], 0, 0, 0);
            }
        __builtin_amdgcn_s_setprio(0);
        __builtin_amdgcn_s_barrier();

        // ---- phase 2: Q(m4-7, n2-3): new B ----
#pragma unroll
        for (int j = 0; j < 2; j++) { bfr[j][0] = rdB(2 + j, 0); bfr[j][1] = rdB(2 + j, 1); }
        __builtin_amdgcn_s_barrier();
        __builtin_amdgcn_s_setprio(1);
#pragma unroll
        for (int i = 0; i < 4; i++)
#pragma unroll
            for (int j = 0; j < 2; j++) {
                acc[4 + i][2 + j] = __builtin_amdgcn_mfma_f32_16x16x32_bf16(af[i][0], bfr[j][0], acc[4 + i][2 + j], 0, 0, 0);
                acc[4 + i][2 + j] = __builtin_amdgcn_mfma_f32_16x16x32_bf16(af[i][1], bfr[j][1], acc[4 + i][2 + j], 0, 0, 0);
            }
        __builtin_amdgcn_s_setprio(0);
        __builtin_amdgcn_s_barrier();

        // ---- phase 3: Q(m0-3, n2-3): reload A m0-3; tile-boundary vmcnt ----
#pragma unroll
        for (int i = 0; i < 4; i++) { af[i][0] = rdA(i, 0); af[i][1] = rdA(i, 1); }
        __builtin_amdgcn_s_barrier();
        __builtin_amdgcn_s_setprio(1);
#pragma unroll
        for (int i = 0; i < 4; i++)
#pragma unroll
            for (int j = 0; j < 2; j++) {
                acc[i][2 + j] = __builtin_amdgcn_mfma_f32_16x16x32_bf16(af[i][0], bfr[j][0], acc[i][2 + j], 0, 0, 0);
                acc[i][2 + j] = __builtin_amdgcn_mfma_f32_16x16x32_bf16(af[i][1], bfr[j][1], acc[i][2 + j], 0, 0, 0);
            }
        __builtin_amdgcn_s_setprio(0);
        // loads for tile t+1 were issued 3 phases ago — wait them, then sync
        asm volatile("s_waitcnt vmcnt(0)" ::: "memory");
        __builtin_amdgcn_s_barrier();
    }
}

// ---------------------------------------------------------------------------
// Double-buffered 2-phase GEMM core (proven) — used by GEMM-C.
// 64B-row LDS layout; 2-bit slot swizzle (slot ^= row&3) on both sides.
// ---------------------------------------------------------------------------
template<int BM, int BN, int S>
__device__ __forceinline__ void gemm_core_db(const u16* __restrict__ A,
                                             const u16* __restrict__ B,
                                             int Kloop, int ld,
                                             int row0, int col0,
                                             u16* smem,
                                             f32x4 (&acc)[BM / 32][BN / 32])
{
    constexpr int MT = BM / 32, NT = BN / 32;
    constexpr int STG = (BM + BN) * 32;     // u16 per stage
    constexpr int SET = STG * S;            // u16 per buffer set
    const int tid  = threadIdx.x;
    const int lane = tid & 63;
    const int wv   = tid >> 6;
    const int wr   = wv >> 1, wc = wv & 1;
    const int lr   = lane & 15, kg = lane >> 4;

#pragma unroll
    for (int i = 0; i < MT; i++)
#pragma unroll
        for (int j = 0; j < NT; j++) {
            f32x4 z = {0.f, 0.f, 0.f, 0.f};
            acc[i][j] = z;
        }

    auto stage_in = [&](u16* set, int k0) {
#pragma unroll
        for (int c = tid; c < BM * 4; c += 256) {
            int row = c >> 2, sl = swz64(c & 3, row);
            const u16* gA = A + (size_t)(row0 + row) * ld + k0 + sl * 8;
#pragma unroll
            for (int s = 0; s < S; s++)
                async_copy16(set + s * STG + c * 8, gA + s * 32);
        }
#pragma unroll
        for (int c = tid; c < BN * 4; c += 256) {
            int row = c >> 2, sl = swz64(c & 3, row);
            const u16* gB = B + (size_t)(col0 + row) * ld + k0 + sl * 8;
#pragma unroll
            for (int s = 0; s < S; s++)
                async_copy16(set + s * STG + BM * 32 + c * 8, gB + s * 32);
        }
    };

    stage_in(smem, 0);
    __syncthreads();           // drain prologue staging

    int p = 0;
    for (int k0 = 0; k0 < Kloop; k0 += 32 * S) {
        if (k0 + 32 * S < Kloop)
            stage_in(smem + (p ^ 1) * SET, k0 + 32 * S);   // prefetch next window
        u16* set = smem + p * SET;
#pragma unroll
        for (int s = 0; s < S; s++) {
            const u16* sA = set + s * STG;
            const u16* sB = sA + BM * 32;
            bf16x8 af[MT], bfr[NT];
#pragma unroll
            for (int i = 0; i < MT; i++) {
                int row = wr * (BM / 2) + i * 16 + lr;
                af[i] = *(const bf16x8*)(sA + (row * 32 + swz64(kg, row) * 8));
            }
#pragma unroll
            for (int j = 0; j < NT; j++) {
                int row = wc * (BN / 2) + j * 16 + lr;
                bfr[j] = *(const bf16x8*)(sB + (row * 32 + swz64(kg, row) * 8));
            }
#pragma unroll
            for (int i = 0; i < MT; i++)
#pragma unroll
                for (int j = 0; j < NT; j++)
                    acc[i][j] = __builtin_amdgcn_mfma_f32_16x16x32_bf16(
                                    af[i], bfr[j], acc[i][j], 0, 0, 0);
        }
        __syncthreads();       // one barrier/window; vmcnt drain overlapped above
        p ^= 1;
    }
}

// ---------------------------------------------------------------------------
// tiny: conn = sigmoid(relu(na@W1+b1)@W2+b2), wts = softmax(act_w). All f32.
// ---------------------------------------------------------------------------
__global__ __launch_bounds__(256)
void k_small(const float* __restrict__ na, const float* __restrict__ W1,
             const float* __restrict__ b1, const float* __restrict__ W2,
             const float* __restrict__ b2, const float* __restrict__ actw,
             float* __restrict__ conn, float* __restrict__ wts)
{
    __shared__ float red[256 * 32];
    __shared__ float hsh[32];
    const int tid = threadIdx.x;
    float h[32];
#pragma unroll
    for (int k = 0; k < 32; k++) h[k] = 0.f;
    for (int u = tid; u < 2048; u += 256) {
        float nav = na[u];
        const float* row = W1 + u * 32;
#pragma unroll
        for (int k = 0; k < 32; k++) h[k] += nav * row[k];
    }
#pragma unroll
    for (int k = 0; k < 32; k++) red[tid * 32 + k] = h[k];
    for (int s = 128; s > 0; s >>= 1) {
        __syncthreads();
        if (tid < s)
#pragma unroll
            for (int k = 0; k < 32; k++) red[tid * 32 + k] += red[(tid + s) * 32 + k];
    }
    __syncthreads();
    if (tid < 32) hsh[tid] = fmaxf(red[tid] + b1[tid], 0.f);
    if (tid == 0) {
        float e[9], m = -1e30f;
        for (int i = 0; i < 9; i++) { e[i] = actw[i]; m = fmaxf(m, e[i]); }
        float s = 0.f;
        for (int i = 0; i < 9; i++) { e[i] = expf(e[i] - m); s += e[i]; }
        for (int i = 0; i < 9; i++) wts[i] = e[i] / s;
    }
    __syncthreads();
    for (int u = tid; u < 2048; u += 256) {
        float a = 0.f;
#pragma unroll
        for (int k = 0; k < 32; k++) a += hsh[k] * W2[k * 2048 + u];
        conn[u] = 1.f / (1.f + expf(-(a + b2[u])));
    }
}

// ---------------------------------------------------------------------------
// gate softmax + y = x*gate (bf16 out). One wave per row n.
// ---------------------------------------------------------------------------
__global__ __launch_bounds__(256)
void k_gate_y(const float* __restrict__ x, const float* __restrict__ gW,
              const float* __restrict__ gb, float* __restrict__ gate,
              u16* __restrict__ y)
{
    const int tid = threadIdx.x, lane = tid & 63, wv = tid >> 6;
    const int n = blockIdx.x * 4 + wv;
    const float* xr = x + (size_t)n * 1024;
    float a0 = 0, a1 = 0, a2 = 0, a3 = 0;
    float xv[16];
#pragma unroll
    for (int s = 0; s < 16; s++) {
        int d = s * 64 + lane;
        float xd = xr[d]; xv[s] = xd;
        float4 g4 = *(const float4*)(gW + d * 4);
        a0 += xd * g4.x; a1 += xd * g4.y; a2 += xd * g4.z; a3 += xd * g4.w;
    }
#pragma unroll
    for (int off = 32; off > 0; off >>= 1) {
        a0 += __shfl_xor(a0, off); a1 += __shfl_xor(a1, off);
        a2 += __shfl_xor(a2, off); a3 += __shfl_xor(a3, off);
    }
    a0 += gb[0]; a1 += gb[1]; a2 += gb[2]; a3 += gb[3];
    float m = fmaxf(fmaxf(a0, a1), fmaxf(a2, a3));
    float e0 = expf(a0 - m), e1 = expf(a1 - m), e2 = expf(a2 - m), e3 = expf(a3 - m);
    float inv = 1.f / (e0 + e1 + e2 + e3);
    float g0 = e0 * inv, g1 = e1 * inv, g2 = e2 * inv, g3 = e3 * inv;
    if (lane == 0) *(float4*)(gate + n * 4) = make_float4(g0, g1, g2, g3);
#pragma unroll
    for (int s = 0; s < 16; s++) {
        int d = s * 64 + lane;
        ushort4 o;
        o.x = f2b(xv[s] * g0); o.y = f2b(xv[s] * g1);
        o.z = f2b(xv[s] * g2); o.w = f2b(xv[s] * g3);
        *(ushort4*)(y + (size_t)n * 4096 + d * 4) = o;
    }
}

// ---------------------------------------------------------------------------
// wmT[u, d*4+b] = w[d,u,b] * sigmoid(delay[d,u,b]); f32 in, bf16 out.
// ---------------------------------------------------------------------------
__global__ __launch_bounds__(256)
void k_wmT(const float* __restrict__ w, const float* __restrict__ delay,
           u16* __restrict__ wmT)
{
    __shared__ __align__(16) ushort4 tile[32][65];
    const int tid = threadIdx.x;
    const int tx = tid & 63, ty = tid >> 6;          // tx: u, ty: d-subset
    const int u0 = blockIdx.x * 64, d0 = blockIdx.y * 32;
#pragma unroll
    for (int i = 0; i < 8; i++) {
        int d = i * 4 + ty;
        size_t idx = ((size_t)(d0 + d) * 2048 + (u0 + tx)) * 4;
        float4 w4 = *(const float4*)(w + idx);
        float4 d4 = *(const float4*)(delay + idx);
        ushort4 o;
        o.x = f2b(w4.x / (1.f + expf(-d4.x)));
        o.y = f2b(w4.y / (1.f + expf(-d4.y)));
        o.z = f2b(w4.z / (1.f + expf(-d4.z)));
        o.w = f2b(w4.w / (1.f + expf(-d4.w)));
        tile[d][tx] = o;
    }
    __syncthreads();
    const int dx = tid & 31, uy = tid >> 5;
#pragma unroll
    for (int i = 0; i < 8; i++) {
        int u = i * 8 + uy;
        *(ushort4*)(wmT + (size_t)(u0 + u) * 4096 + (d0 + dx) * 4) = tile[dx][u];
    }
}

// ---------------------------------------------------------------------------
// transpose + cast: in[R,C] f32 -> out[C,R] bf16, 64x64 tiles
// ---------------------------------------------------------------------------
__global__ __launch_bounds__(256)
void k_transpose(const float* __restrict__ in, u16* __restrict__ out, int R, int C)
{
    __shared__ __align__(16) u16 t[64][68];
    const int tid = threadIdx.x, tx = tid & 15, ty = tid >> 4;
    const int c0 = blockIdx.x * 64, r0 = blockIdx.y * 64;
#pragma unroll
    for (int i = 0; i < 4; i++) {
        int r = r0 + ty + i * 16;
        float4 v = *(const float4*)(in + (size_t)r * C + c0 + tx * 4);
        t[tx * 4 + 0][ty + i * 16] = f2b(v.x); t[tx * 4 + 1][ty + i * 16] = f2b(v.y);
        t[tx * 4 + 2][ty + i * 16] = f2b(v.z); t[tx * 4 + 3][ty + i * 16] = f2b(v.w);
    }
    __syncthreads();
#pragma unroll
    for (int i = 0; i < 4; i++) {
        int c = ty + i * 16;
        ushort4 v;
        v.x = t[c][tx * 4 + 0]; v.y = t[c][tx * 4 + 1];
        v.z = t[c][tx * 4 + 2]; v.w = t[c][tx * 4 + 3];
        *(ushort4*)(out + (size_t)(c0 + c) * R + r0 + tx * 4) = v;
    }
}

// ---------------------------------------------------------------------------
// 8-way activation blend
// ---------------------------------------------------------------------------
__device__ __forceinline__ float act_blend(float a,
    float w0, float w1, float w2, float w3,
    float w4, float w5, float w6, float w7)
{
    float sig = 1.f / (1.f + expf(-a));
    float elu = (a > 0.f) ? a : (expf(a) - 1.f);
    float th  = tanhf(a);
    float rel = fmaxf(a, 0.f);
    float sil = a * sig;
    float gel = a * 0.5f * (1.f + erff(a * 0.70710678118654752f));
    float sel = (a > 0.f) ? 1.0507009873554805f * a
                          : 1.0507009873554805f * 1.6732632423543772f * (expf(a) - 1.f);
    float sp  = (a > 20.f) ? a : log1pf(expf(a));
    float mish = a * tanhf(sp);
    return w0 * sig + w1 * elu + w2 * th + w3 * rel + w4 * sil + w5 * gel
         + w6 * sel + w7 * mish;
}

// ---------------------------------------------------------------------------
// GEMM-A (8-phase 256^2, split-K): P[z][n,u] partial = y@wmT^T over K-chunk z.
// grid (8, 8, 4), 512 thr, LDS 128 KiB -> 256 blocks, 1/CU.
// ---------------------------------------------------------------------------
__global__ __launch_bounds__(512, 2)
void k_gemm_a8(const u16* __restrict__ A, const u16* __restrict__ B,
               float* __restrict__ P)
{
    __shared__ __align__(16) char lds[131072];
    const int row0 = blockIdx.y * 256, col0 = blockIdx.x * 256;
    const u16* Ac = A + (size_t)blockIdx.z * 1024;
    const u16* Bc = B + (size_t)blockIdx.z * 1024;

    f32x4 acc[8][4];
    gemm256_core8(Ac, Bc, 16, 4096, row0, col0, lds, acc);

    float* Pz = P + (size_t)blockIdx.z * 2048 * 2048;
    const int tid = threadIdx.x, lane = tid & 63, wv = tid >> 6;
    const int wr = wv >> 2, wc = wv & 3, lr = lane & 15, kg = lane >> 4;
#pragma unroll
    for (int i = 0; i < 8; i++)
#pragma unroll
        for (int r = 0; r < 4; r++) {
            int n = row0 + wr * 128 + i * 16 + kg * 4 + r;
            size_t ob = (size_t)n * 2048;
#pragma unroll
            for (int j = 0; j < 4; j++)
                Pz[ob + col0 + wc * 64 + j * 16 + lr] = acc[i][j][r];
        }
}

// ---------------------------------------------------------------------------
// reduce 4 split-K partials + GEMM-A epilogue:
// blend[n,u] = blend8(relu((sum_s P[s][n,u] + gate[n]·b[u])*conn[u]*mask[u]))
// ---------------------------------------------------------------------------
__global__ __launch_bounds__(256)
void k_reduce_blend(const float* __restrict__ P, const float* __restrict__ gate,
                    const float* __restrict__ conn, const float* __restrict__ mask,
                    const float* __restrict__ wts, const float* __restrict__ bbias,
                    u16* __restrict__ blend)
{
    constexpr size_t SL = (size_t)2048 * 2048;
    const int n  = blockIdx.x;
    const int u0 = threadIdx.x * 8;
    const float* base = P + (size_t)n * 2048 + u0;

    float v[8];
#pragma unroll
    for (int h = 0; h < 2; h++) {
        float4 a = *(const float4*)(base + h * 4);
        float4 b = *(const float4*)(base + SL + h * 4);
        float4 c = *(const float4*)(base + 2 * SL + h * 4);
        float4 d = *(const float4*)(base + 3 * SL + h * 4);
        v[h * 4 + 0] = a.x + b.x + c.x + d.x;
        v[h * 4 + 1] = a.y + b.y + c.y + d.y;
        v[h * 4 + 2] = a.z + b.z + c.z + d.z;
        v[h * 4 + 3] = a.w + b.w + c.w + d.w;
    }
    float4 g = *(const float4*)(gate + n * 4);
    const float w0 = wts[0], w1 = wts[1], w2 = wts[2], w3 = wts[3];
    const float w4 = wts[4], w5 = wts[5], w6 = wts[6], w7 = wts[7];

    ushort4 o[2];
#pragma unroll
    for (int j = 0; j < 8; j++) {
        int u = u0 + j;
        float4 b4 = *(const float4*)(bbias + u * 4);
        float z = v[j] + g.x * b4.x + g.y * b4.y + g.z * b4.z + g.w * b4.w;
        float a = fmaxf(z * conn[u] * mask[u], 0.f);
        u16 r = f2b(act_blend(a, w0, w1, w2, w3, w4, w5, w6, w7));
        ((u16*)o)[j] = r;
    }
    *(ushort4*)(blend + (size_t)n * 2048 + u0)     = o[0];
    *(ushort4*)(blend + (size_t)n * 2048 + u0 + 4) = o[1];
}

// ---------------------------------------------------------------------------
// GEMM-B (8-phase 256^2): logits[n,m] = blend@read_W^T + read_b (bf16 out)
// grid (32, 8), 512 thr -> 256 blocks, 1/CU.
// ---------------------------------------------------------------------------
__global__ __launch_bounds__(512, 2)
void k_gemm_logits8(const u16* __restrict__ BL, const u16* __restrict__ RWT,
                    const float* __restrict__ rbias, u16* __restrict__ out)
{
    __shared__ __align__(16) char lds[131072];
    const int row0 = blockIdx.y * 256, col0 = blockIdx.x * 256;

    f32x4 acc[8][4];
    gemm256_core8(BL, RWT, 32, 2048, row0, col0, lds, acc);

    const int tid = threadIdx.x, lane = tid & 63, wv = tid >> 6;
    const int wr = wv >> 2, wc = wv & 3, lr = lane & 15, kg = lane >> 4;
    float rb[4]; int mm[4];
#pragma unroll
    for (int j = 0; j < 4; j++) {
        mm[j] = col0 + wc * 64 + j * 16 + lr;
        rb[j] = rbias[mm[j]];
    }
#pragma unroll
    for (int i = 0; i < 8; i++)
#pragma unroll
        for (int r = 0; r < 4; r++) {
            int n = row0 + wr * 128 + i * 16 + kg * 4 + r;
            size_t ob = (size_t)n * 8192;
#pragma unroll
            for (int j = 0; j < 4; j++)
                out[ob + mm[j]] = f2b(acc[i][j][r] + rb[j]);
        }
}

// ---------------------------------------------------------------------------
// in-place row softmax over 8192 bf16 (one block per row, values in registers)
// ---------------------------------------------------------------------------
__global__ __launch_bounds__(256)
void k_softmax(u16* __restrict__ buf)
{
    __shared__ float red[8];
    const int tid = threadIdx.x, lane = tid & 63, wv = tid >> 6;
    u16* row = buf + (size_t)blockIdx.x * 8192;
    float v[32];
    float mx = -1e30f;
#pragma unroll
    for (int s = 0; s < 8; s++) {
        ushort4 u4 = *(const ushort4*)(row + (s * 256 + tid) * 4);
        float a = b2f(u4.x), b = b2f(u4.y), c = b2f(u4.z), d = b2f(u4.w);
        v[s * 4 + 0] = a; v[s * 4 + 1] = b; v[s * 4 + 2] = c; v[s * 4 + 3] = d;
        mx = fmaxf(mx, fmaxf(fmaxf(a, b), fmaxf(c, d)));
    }
#pragma unroll
    for (int off = 32; off > 0; off >>= 1) mx = fmaxf(mx, __shfl_xor(mx, off));
    if (lane == 0) red[wv] = mx;
    __syncthreads();
    mx = fmaxf(fmaxf(red[0], red[1]), fmaxf(red[2], red[3]));
    float sum = 0.f;
#pragma unroll
    for (int k = 0; k < 32; k++) { v[k] = expf(v[k] - mx); sum += v[k]; }
#pragma unroll
    for (int off = 32; off > 0; off >>= 1) sum += __shfl_xor(sum, off);
    if (lane == 0) red[4 + wv] = sum;
    __syncthreads();
    float inv = 1.f / (red[4] + red[5] + red[6] + red[7]);
#pragma unroll
    for (int s = 0; s < 8; s++) {
        ushort4 o;
        o.x = f2b(v[s * 4 + 0] * inv); o.y = f2b(v[s * 4 + 1] * inv);
        o.z = f2b(v[s * 4 + 2] * inv); o.w = f2b(v[s * 4 + 3] * inv);
        *(ushort4*)(row + (s * 256 + tid) * 4) = o;
    }
}

// ---------------------------------------------------------------------------
// GEMM-C (2-phase 128^2 split-K): P[z][n,md] partial = attn @ memory chunk.
// ---------------------------------------------------------------------------
template<int BM, int BN, int NCOL>
__global__ __launch_bounds__(256, 4)
void k_gemm_partial(const u16* __restrict__ A, const u16* __restrict__ B,
                    int Kchunk, int ld, float* __restrict__ P)
{
    constexpr int MT = BM / 32, NT = BN / 32;
    __shared__ __align__(16) u16 smem[2 * (BM + BN) * 32];

    const int nx = gridDim.x, ny = gridDim.y;
    const int f  = blockIdx.x + nx * blockIdx.y;
    const int ch = (nx * ny) >> 3;                 // chunk per XCD
    const int sw = (f & 7) * ch + (f >> 3);        // bijective (nwg%8==0)
    const int bx = sw % nx, by = sw / nx;
    const int row0 = by * BM, col0 = bx * BN;

    const u16* Ac = A + (size_t)blockIdx.z * Kchunk;
    const u16* Bc = B + (size_t)blockIdx.z * Kchunk;

    f32x4 acc[MT][NT];
    gemm_core_db<BM, BN, 1>(Ac, Bc, Kchunk, ld, row0, col0, smem, acc);

    float* Pz = P + (size_t)blockIdx.z * 2048 * NCOL;
    const int tid = threadIdx.x, lane = tid & 63, wv = tid >> 6;
    const int wr = wv >> 1, wc = wv & 1, lr = lane & 15, kg = lane >> 4;
#pragma unroll
    for (int i = 0; i < MT; i++)
#pragma unroll
        for (int r = 0; r < 4; r++) {
            int n = row0 + wr * (BM / 2) + i * 16 + kg * 4 + r;
            size_t ob = (size_t)n * NCOL;
#pragma unroll
            for (int j = 0; j < NT; j++)
                Pz[ob + col0 + wc * (BN / 2) + j * 16 + lr] = acc[i][j][r];
        }
}

// ---------------------------------------------------------------------------
// reduce 4 split-K partials into final f32 output (GEMM-C tail)
// ---------------------------------------------------------------------------
__global__ __launch_bounds__(256)
void k_reduce_out(const float* __restrict__ P, float* __restrict__ out)
{
    constexpr size_t SL = (size_t)2048 * 1024;
    size_t i = ((size_t)blockIdx.x * 256 + threadIdx.x) * 4;
    float4 a = *(const float4*)(P + i);
    float4 b = *(const float4*)(P + SL + i);
    float4 c = *(const float4*)(P + 2 * SL + i);
    float4 d = *(const float4*)(P + 3 * SL + i);
    float4 o;
    o.x = a.x + b.x + c.x + d.x;
    o.y = a.y + b.y + c.y + d.y;
    o.z = a.z + b.z + c.z + d.z;
    o.w = a.w + b.w + c.w + d.w;
    *(float4*)(out + i) = o;
}

// sentinel: distinctive output if workspace is too small (absmax ~12345)
__global__ void k_fill(float* out, int n)
{
    int i = blockIdx.x * 256 + threadIdx.x;
    if (i < n) out[i] = 12345.f;
}

// ---------------------------------------------------------------------------
extern "C" void kernel_launch(void* const* d_in, const int* in_sizes, int n_in,
                              void* d_out, int out_size, void* d_ws, size_t ws_size,
                              hipStream_t stream)
{
    const float* x     = (const float*)d_in[0];
    const float* w     = (const float*)d_in[1];
    const float* delay = (const float*)d_in[2];
    const float* bb    = (const float*)d_in[3];
    const float* gW    = (const float*)d_in[4];
    const float* gb    = (const float*)d_in[5];
    const float* na    = (const float*)d_in[6];
    const float* cW1   = (const float*)d_in[7];
    const float* cb1   = (const float*)d_in[8];
    const float* cW2   = (const float*)d_in[9];
    const float* cb2   = (const float*)d_in[10];
    const float* mask  = (const float*)d_in[11];
    const float* actw  = (const float*)d_in[12];
    const float* rW    = (const float*)d_in[13];
    const float* rb    = (const float*)d_in[14];
    const float* mem   = (const float*)d_in[15];
    (void)in_sizes; (void)n_in;

    char* ws = (char*)d_ws;
    size_t off = 0;
    auto alloc = [&](size_t bytes) {
        size_t o = off; off += (bytes + 255) & ~(size_t)255; return o;
    };
    size_t o_wts   = alloc(9 * 4);
    size_t o_gate  = alloc(2048 * 4 * 4);
    size_t o_conn  = alloc(2048 * 4);
    size_t o_y     = alloc((size_t)2048 * 4096 * 2);   // y; later aliased as memT
    size_t o_wmT   = alloc((size_t)2048 * 4096 * 2);
    size_t o_blend = alloc((size_t)2048 * 2048 * 2);
    size_t o_rwT   = alloc((size_t)8192 * 2048 * 2);   // rwT; also split-K partials
    size_t o_log   = alloc((size_t)2048 * 8192 * 2);   // logits; A-partials overflow

    if (off > ws_size) {   // loud, distinguishable failure mode
        k_fill<<<(out_size + 255) / 256, 256, 0, stream>>>((float*)d_out, out_size);
        return;
    }

    float* wts   = (float*)(ws + o_wts);
    float* gate  = (float*)(ws + o_gate);
    float* conn  = (float*)(ws + o_conn);
    u16* y       = (u16*)(ws + o_y);
    u16* wmT     = (u16*)(ws + o_wmT);
    u16* blend   = (u16*)(ws + o_blend);
    u16* rwT     = (u16*)(ws + o_rwT);
    u16* logits  = (u16*)(ws + o_log);
    u16* memT    = y;   // y dead after GEMM-A; same size (16 MB)

    // split-K partial buffers, aliased into lifetime holes:
    //   A-partials: 4 x 2048 x 2048 f32 = 64 MB @ [o_rwT, o_rwT+64MB)
    //     (rwT written AFTER reduce_blend; logits written AFTER that) — no overlap.
    //   C-partials: 4 x 2048 x 1024 f32 = 32 MB @ o_rwT (rwT dead after logits).
    float* pA = (float*)(ws + o_rwT);
    float* pC = (float*)(ws + o_rwT);

    k_small<<<1, 256, 0, stream>>>(na, cW1, cb1, cW2, cb2, actw, conn, wts);
    k_gate_y<<<512, 256, 0, stream>>>(x, gW, gb, gate, y);
    k_wmT<<<dim3(32, 32), 256, 0, stream>>>(w, delay, wmT);

    // GEMM-A: partials = y[2048,4096] @ wmT[2048,4096]^T, split-K=4 (K=1024 each)
    k_gemm_a8<<<dim3(8, 8, 4), 512, 0, stream>>>(y, wmT, pA);
    k_reduce_blend<<<2048, 256, 0, stream>>>(pA, gate, conn, mask, wts, bb, blend);

    k_transpose<<<dim3(128, 32), 256, 0, stream>>>(rW, rwT, 2048, 8192);
    k_gemm_logits8<<<dim3(32, 8), 512, 0, stream>>>(blend, rwT, rb, logits);
    k_softmax<<<2048, 256, 0, stream>>>(logits);

    k_transpose<<<dim3(16, 128), 256, 0, stream>>>(mem, memT, 8192, 1024);

    // GEMM-C: out-partials = attn[2048,8192] @ memT[1024,8192]^T, split-K=4 (K=2048)
    k_gemm_partial<128, 128, 1024><<<dim3(8, 16, 4), 256, 0, stream>>>(
        logits, memT, 2048, 8192, pC);
    k_reduce_out<<<2048, 256, 0, stream>>>(pC, (float*)d_out);
}

// Round 5
// 432.284 us; speedup vs baseline: 1.4464x; 1.0490x over previous
//
#include <hip/hip_runtime.h>

// ============================================================================
// PlasticityModelMoE — MI355X (gfx950). Inputs f32, output f32, bf16 MFMA.
// R12: 8-phase core scheduling fixes (conflicts already 0 after R11):
//   (1) spread staging: A-loads of tile t+1 at ph0, B-loads at ph1 (m196:
//       burst staging hurts; per-phase interleave is the lever). vmcnt(0) at
//       ph3 then waits on >=2-phase-old loads (~2800cyc >> 900cyc HBM) - free.
//   (2) af[0-3] kept in registers across the tile: ph3 re-reads eliminated
//       (LDS reads/tile 36 -> 24, -33%); ph3 is a pure-register MFMA phase.
//   (3) ph3's pre-MFMA barrier dropped (no LDS access between ph2-post-barrier
//       and ph3 MFMA) -> 7 barriers/tile.
// GEMM-C: 2-phase core S=1 -> S=2 (BK=64/window, half the barriers; 64KB LDS
// still = its 2 blocks/CU grid).
// ============================================================================

typedef unsigned short u16;
typedef __attribute__((ext_vector_type(8))) short bf16x8;   // 8 bf16 = 4 VGPRs
typedef __attribute__((ext_vector_type(4))) float f32x4;

__device__ __forceinline__ float b2f(u16 h) {
    union { unsigned u; float f; } v; v.u = ((unsigned)h) << 16; return v.f;
}
__device__ __forceinline__ u16 f2b(float f) {
    union { float f; unsigned u; } v; v.f = f;
    unsigned u = v.u;
    return (u16)((u + 0x7fffu + ((u >> 16) & 1u)) >> 16);   // round-nearest-even
}

// async global->LDS, 16B per lane (wave-uniform base + lane*16 — m97 pattern).
__device__ __forceinline__ void async_copy16(void* lds, const void* g) {
    __builtin_amdgcn_global_load_lds(
        (__attribute__((address_space(1))) void*)(g),
        (__attribute__((address_space(3))) void*)(lds), 16, 0, 0);
}

// 3-bit swizzle for 128B-row tiles: 16B-slot bits [6:4] ^= row bits [9:7].
// Involution; conflict-free ds_read_b128 (R11: BANK_CONFLICT -> 0).
__device__ __forceinline__ int swz(int o) { return o ^ (((o >> 7) & 7) << 4); }

// 2-bit swizzle for 64B-row tiles (2-phase core): slot ^= row&3. 8way->4way.
__device__ __forceinline__ int swz64(int kg, int row) { return kg ^ (row & 3); }

// ---------------------------------------------------------------------------
// 256x256 8-phase GEMM core (T2+T3+T4+T5). C[256,256] = A[256,K]*B[256,K]^T.
// 512 thr / 8 waves as 2(M) x 4(N); per-wave 128x64; acc[8][4] f32x4.
// lds: 128 KiB = 2 bufs x { A: 2x(128x64) halves, B: same } bf16, swizzled.
// Ktiles = K/64 (>=2). ld = row stride of A and B in elements.
// Each wave reads ONLY its own A-half (wr) and B-half (wc>>1).
// ---------------------------------------------------------------------------
__device__ __forceinline__ void stage_tile256(const u16* __restrict__ src, int ld,
                                              int base0, int k0,
                                              char* ldsbase, int tid)
{
#pragma unroll
    for (int h = 0; h < 2; h++)
#pragma unroll
        for (int it = 0; it < 2; it++) {
            int o = it * 8192 + tid * 16;          // linear LDS byte offset
            int s = swz(o);                        // logical source offset
            int r = s >> 7;                        // row within 128-row half
            int c = (s & 127) >> 1;                // bf16 col (multiple of 8)
            async_copy16(ldsbase + h * 16384 + o,
                         src + (size_t)(base0 + h * 128 + r) * ld + k0 + c);
        }
}

__device__ __forceinline__ void gemm256_core8(const u16* __restrict__ A,
                                              const u16* __restrict__ B,
                                              int Ktiles, int ld,
                                              int row0, int col0,
                                              char* lds, f32x4 (&acc)[8][4])
{
    const int tid  = threadIdx.x;
    const int lane = tid & 63;
    const int wv   = tid >> 6;
    const int wr   = wv >> 2;          // 0..1  (M half)
    const int wc   = wv & 3;           // 0..3  (N quarter)
    const int lr   = lane & 15, kg = lane >> 4;

#pragma unroll
    for (int i = 0; i < 8; i++)
#pragma unroll
        for (int j = 0; j < 4; j++) {
            f32x4 z = {0.f, 0.f, 0.f, 0.f};
            acc[i][j] = z;
        }

    // prologue: stage tile 0 into buf 0
    stage_tile256(A, ld, row0, 0, lds, tid);
    stage_tile256(B, ld, col0, 0, lds + 32768, tid);
    asm volatile("s_waitcnt vmcnt(0)" ::: "memory");
    __builtin_amdgcn_s_barrier();

    bf16x8 af03[4][2], af47[4][2], bfr[2][2];

    for (int t = 0; t < Ktiles; t++) {
        const int buf = (t & 1) << 16;
        const char* sA = lds + buf + wr * 16384;
        const char* sB = lds + buf + 32768 + ((wc >> 1) * 16384);
        char* nb = lds + (((t + 1) & 1) << 16);
        const bool pf = (t + 1 < Ktiles);

        auto rdA = [&](int i, int ks) {
            int off = (i * 16 + lr) * 128 + ks * 64 + kg * 16;
            return *(const bf16x8*)(sA + swz(off));
        };
        auto rdB = [&](int j, int ks) {
            int off = ((wc & 1) * 64 + j * 16 + lr) * 128 + ks * 64 + kg * 16;
            return *(const bf16x8*)(sB + swz(off));
        };

        // ---- phase 0: read A m0-3 + B n0-1; stage A(t+1); MFMA m0-3 x n0-1
#pragma unroll
        for (int i = 0; i < 4; i++) { af03[i][0] = rdA(i, 0); af03[i][1] = rdA(i, 1); }
#pragma unroll
        for (int j = 0; j < 2; j++) { bfr[j][0] = rdB(j, 0); bfr[j][1] = rdB(j, 1); }
        if (pf) stage_tile256(A, ld, row0, (t + 1) * 64, nb, tid);
        __builtin_amdgcn_s_barrier();
        __builtin_amdgcn_s_setprio(1);
#pragma unroll
        for (int i = 0; i < 4; i++)
#pragma unroll
            for (int j = 0; j < 2; j++) {
                acc[i][j] = __builtin_amdgcn_mfma_f32_16x16x32_bf16(af03[i][0], bfr[j][0], acc[i][j], 0, 0, 0);
                acc[i][j] = __builtin_amdgcn_mfma_f32_16x16x32_bf16(af03[i][1], bfr[j][1], acc[i][j], 0, 0, 0);
            }
        __builtin_amdgcn_s_setprio(0);
        __builtin_amdgcn_s_barrier();

        // ---- phase 1: read A m4-7; stage B(t+1); MFMA m4-7 x n0-1 ----
#pragma unroll
        for (int i = 0; i < 4; i++) { af47[i][0] = rdA(4 + i, 0); af47[i][1] = rdA(4 + i, 1); }
        if (pf) stage_tile256(B, ld, col0, (t + 1) * 64, nb + 32768, tid);
        __builtin_amdgcn_s_barrier();
        __builtin_amdgcn_s_setprio(1);
#pragma unroll
        for (int i = 0; i < 4; i++)
#pragma unroll
            for (int j = 0; j < 2; j++) {
                acc[4 + i][j] = __builtin_amdgcn_mfma_f32_16x16x32_bf16(af47[i][0], bfr[j][0], acc[4 + i][j], 0, 0, 0);
                acc[4 + i][j] = __builtin_amdgcn_mfma_f32_16x16x32_bf16(af47[i][1], bfr[j][1], acc[4 + i][j], 0, 0, 0);
            }
        __builtin_amdgcn_s_setprio(0);
        __builtin_amdgcn_s_barrier();

        // ---- phase 2: read B n2-3; MFMA m4-7 x n2-3 ----
#pragma unroll
        for (int j = 0; j < 2; j++) { bfr[j][0] = rdB(2 + j, 0); bfr[j][1] = rdB(2 + j, 1); }
        __builtin_amdgcn_s_barrier();
        __builtin_amdgcn_s_setprio(1);
#pragma unroll
        for (int i = 0; i < 4; i++)
#pragma unroll
            for (int j = 0; j < 2; j++) {
                acc[4 + i][2 + j] = __builtin_amdgcn_mfma_f32_16x16x32_bf16(af47[i][0], bfr[j][0], acc[4 + i][2 + j], 0, 0, 0);
                acc[4 + i][2 + j] = __builtin_amdgcn_mfma_f32_16x16x32_bf16(af47[i][1], bfr[j][1], acc[4 + i][2 + j], 0, 0, 0);
            }
        __builtin_amdgcn_s_setprio(0);
        __builtin_amdgcn_s_barrier();

        // ---- phase 3: pure-register MFMA m0-3 x n2-3 (af03 still live);
        //      tile-boundary vmcnt (loads are >=2 phases old) + barrier ----
        __builtin_amdgcn_s_setprio(1);
#pragma unroll
        for (int i = 0; i < 4; i++)
#pragma unroll
            for (int j = 0; j < 2; j++) {
                acc[i][2 + j] = __builtin_amdgcn_mfma_f32_16x16x32_bf16(af03[i][0], bfr[j][0], acc[i][2 + j], 0, 0, 0);
                acc[i][2 + j] = __builtin_amdgcn_mfma_f32_16x16x32_bf16(af03[i][1], bfr[j][1], acc[i][2 + j], 0, 0, 0);
            }
        __builtin_amdgcn_s_setprio(0);
        asm volatile("s_waitcnt vmcnt(0)" ::: "memory");
        __builtin_amdgcn_s_barrier();
    }
}

// ---------------------------------------------------------------------------
// Double-buffered 2-phase GEMM core (proven) — used by GEMM-C. S windows of
// BK=32; 64B-row LDS; 2-bit slot swizzle (slot ^= row&3) on both sides.
// ---------------------------------------------------------------------------
template<int BM, int BN, int S>
__device__ __forceinline__ void gemm_core_db(const u16* __restrict__ A,
                                             const u16* __restrict__ B,
                                             int Kloop, int ld,
                                             int row0, int col0,
                                             u16* smem,
                                             f32x4 (&acc)[BM / 32][BN / 32])
{
    constexpr int MT = BM / 32, NT = BN / 32;
    constexpr int STG = (BM + BN) * 32;     // u16 per stage
    constexpr int SET = STG * S;            // u16 per buffer set
    const int tid  = threadIdx.x;
    const int lane = tid & 63;
    const int wv   = tid >> 6;
    const int wr   = wv >> 1, wc = wv & 1;
    const int lr   = lane & 15, kg = lane >> 4;

#pragma unroll
    for (int i = 0; i < MT; i++)
#pragma unroll
        for (int j = 0; j < NT; j++) {
            f32x4 z = {0.f, 0.f, 0.f, 0.f};
            acc[i][j] = z;
        }

    auto stage_in = [&](u16* set, int k0) {
#pragma unroll
        for (int c = tid; c < BM * 4; c += 256) {
            int row = c >> 2, sl = swz64(c & 3, row);
            const u16* gA = A + (size_t)(row0 + row) * ld + k0 + sl * 8;
#pragma unroll
            for (int s = 0; s < S; s++)
                async_copy16(set + s * STG + c * 8, gA + s * 32);
        }
#pragma unroll
        for (int c = tid; c < BN * 4; c += 256) {
            int row = c >> 2, sl = swz64(c & 3, row);
            const u16* gB = B + (size_t)(col0 + row) * ld + k0 + sl * 8;
#pragma unroll
            for (int s = 0; s < S; s++)
                async_copy16(set + s * STG + BM * 32 + c * 8, gB + s * 32);
        }
    };

    stage_in(smem, 0);
    __syncthreads();           // drain prologue staging

    int p = 0;
    for (int k0 = 0; k0 < Kloop; k0 += 32 * S) {
        if (k0 + 32 * S < Kloop)
            stage_in(smem + (p ^ 1) * SET, k0 + 32 * S);   // prefetch next window
        u16* set = smem + p * SET;
#pragma unroll
        for (int s = 0; s < S; s++) {
            const u16* sA = set + s * STG;
            const u16* sB = sA + BM * 32;
            bf16x8 af[MT], bfr[NT];
#pragma unroll
            for (int i = 0; i < MT; i++) {
                int row = wr * (BM / 2) + i * 16 + lr;
                af[i] = *(const bf16x8*)(sA + (row * 32 + swz64(kg, row) * 8));
            }
#pragma unroll
            for (int j = 0; j < NT; j++) {
                int row = wc * (BN / 2) + j * 16 + lr;
                bfr[j] = *(const bf16x8*)(sB + (row * 32 + swz64(kg, row) * 8));
            }
#pragma unroll
            for (int i = 0; i < MT; i++)
#pragma unroll
                for (int j = 0; j < NT; j++)
                    acc[i][j] = __builtin_amdgcn_mfma_f32_16x16x32_bf16(
                                    af[i], bfr[j], acc[i][j], 0, 0, 0);
        }
        __syncthreads();       // one barrier/window; vmcnt drain overlapped above
        p ^= 1;
    }
}

// ---------------------------------------------------------------------------
// tiny: conn = sigmoid(relu(na@W1+b1)@W2+b2), wts = softmax(act_w). All f32.
// ---------------------------------------------------------------------------
__global__ __launch_bounds__(256)
void k_small(const float* __restrict__ na, const float* __restrict__ W1,
             const float* __restrict__ b1, const float* __restrict__ W2,
             const float* __restrict__ b2, const float* __restrict__ actw,
             float* __restrict__ conn, float* __restrict__ wts)
{
    __shared__ float red[256 * 32];
    __shared__ float hsh[32];
    const int tid = threadIdx.x;
    float h[32];
#pragma unroll
    for (int k = 0; k < 32; k++) h[k] = 0.f;
    for (int u = tid; u < 2048; u += 256) {
        float nav = na[u];
        const float* row = W1 + u * 32;
#pragma unroll
        for (int k = 0; k < 32; k++) h[k] += nav * row[k];
    }
#pragma unroll
    for (int k = 0; k < 32; k++) red[tid * 32 + k] = h[k];
    for (int s = 128; s > 0; s >>= 1) {
        __syncthreads();
        if (tid < s)
#pragma unroll
            for (int k = 0; k < 32; k++) red[tid * 32 + k] += red[(tid + s) * 32 + k];
    }
    __syncthreads();
    if (tid < 32) hsh[tid] = fmaxf(red[tid] + b1[tid], 0.f);
    if (tid == 0) {
        float e[9], m = -1e30f;
        for (int i = 0; i < 9; i++) { e[i] = actw[i]; m = fmaxf(m, e[i]); }
        float s = 0.f;
        for (int i = 0; i < 9; i++) { e[i] = expf(e[i] - m); s += e[i]; }
        for (int i = 0; i < 9; i++) wts[i] = e[i] / s;
    }
    __syncthreads();
    for (int u = tid; u < 2048; u += 256) {
        float a = 0.f;
#pragma unroll
        for (int k = 0; k < 32; k++) a += hsh[k] * W2[k * 2048 + u];
        conn[u] = 1.f / (1.f + expf(-(a + b2[u])));
    }
}

// ---------------------------------------------------------------------------
// gate softmax + y = x*gate (bf16 out). One wave per row n.
// ---------------------------------------------------------------------------
__global__ __launch_bounds__(256)
void k_gate_y(const float* __restrict__ x, const float* __restrict__ gW,
              const float* __restrict__ gb, float* __restrict__ gate,
              u16* __restrict__ y)
{
    const int tid = threadIdx.x, lane = tid & 63, wv = tid >> 6;
    const int n = blockIdx.x * 4 + wv;
    const float* xr = x + (size_t)n * 1024;
    float a0 = 0, a1 = 0, a2 = 0, a3 = 0;
    float xv[16];
#pragma unroll
    for (int s = 0; s < 16; s++) {
        int d = s * 64 + lane;
        float xd = xr[d]; xv[s] = xd;
        float4 g4 = *(const float4*)(gW + d * 4);
        a0 += xd * g4.x; a1 += xd * g4.y; a2 += xd * g4.z; a3 += xd * g4.w;
    }
#pragma unroll
    for (int off = 32; off > 0; off >>= 1) {
        a0 += __shfl_xor(a0, off); a1 += __shfl_xor(a1, off);
        a2 += __shfl_xor(a2, off); a3 += __shfl_xor(a3, off);
    }
    a0 += gb[0]; a1 += gb[1]; a2 += gb[2]; a3 += gb[3];
    float m = fmaxf(fmaxf(a0, a1), fmaxf(a2, a3));
    float e0 = expf(a0 - m), e1 = expf(a1 - m), e2 = expf(a2 - m), e3 = expf(a3 - m);
    float inv = 1.f / (e0 + e1 + e2 + e3);
    float g0 = e0 * inv, g1 = e1 * inv, g2 = e2 * inv, g3 = e3 * inv;
    if (lane == 0) *(float4*)(gate + n * 4) = make_float4(g0, g1, g2, g3);
#pragma unroll
    for (int s = 0; s < 16; s++) {
        int d = s * 64 + lane;
        ushort4 o;
        o.x = f2b(xv[s] * g0); o.y = f2b(xv[s] * g1);
        o.z = f2b(xv[s] * g2); o.w = f2b(xv[s] * g3);
        *(ushort4*)(y + (size_t)n * 4096 + d * 4) = o;
    }
}

// ---------------------------------------------------------------------------
// wmT[u, d*4+b] = w[d,u,b] * sigmoid(delay[d,u,b]); f32 in, bf16 out.
// ---------------------------------------------------------------------------
__global__ __launch_bounds__(256)
void k_wmT(const float* __restrict__ w, const float* __restrict__ delay,
           u16* __restrict__ wmT)
{
    __shared__ __align__(16) ushort4 tile[32][65];
    const int tid = threadIdx.x;
    const int tx = tid & 63, ty = tid >> 6;          // tx: u, ty: d-subset
    const int u0 = blockIdx.x * 64, d0 = blockIdx.y * 32;
#pragma unroll
    for (int i = 0; i < 8; i++) {
        int d = i * 4 + ty;
        size_t idx = ((size_t)(d0 + d) * 2048 + (u0 + tx)) * 4;
        float4 w4 = *(const float4*)(w + idx);
        float4 d4 = *(const float4*)(delay + idx);
        ushort4 o;
        o.x = f2b(w4.x / (1.f + expf(-d4.x)));
        o.y = f2b(w4.y / (1.f + expf(-d4.y)));
        o.z = f2b(w4.z / (1.f + expf(-d4.z)));
        o.w = f2b(w4.w / (1.f + expf(-d4.w)));
        tile[d][tx] = o;
    }
    __syncthreads();
    const int dx = tid & 31, uy = tid >> 5;
#pragma unroll
    for (int i = 0; i < 8; i++) {
        int u = i * 8 + uy;
        *(ushort4*)(wmT + (size_t)(u0 + u) * 4096 + (d0 + dx) * 4) = tile[dx][u];
    }
}

// ---------------------------------------------------------------------------
// transpose + cast: in[R,C] f32 -> out[C,R] bf16, 64x64 tiles
// ---------------------------------------------------------------------------
__global__ __launch_bounds__(256)
void k_transpose(const float* __restrict__ in, u16* __restrict__ out, int R, int C)
{
    __shared__ __align__(16) u16 t[64][68];
    const int tid = threadIdx.x, tx = tid & 15, ty = tid >> 4;
    const int c0 = blockIdx.x * 64, r0 = blockIdx.y * 64;
#pragma unroll
    for (int i = 0; i < 4; i++) {
        int r = r0 + ty + i * 16;
        float4 v = *(const float4*)(in + (size_t)r * C + c0 + tx * 4);
        t[tx * 4 + 0][ty + i * 16] = f2b(v.x); t[tx * 4 + 1][ty + i * 16] = f2b(v.y);
        t[tx * 4 + 2][ty + i * 16] = f2b(v.z); t[tx * 4 + 3][ty + i * 16] = f2b(v.w);
    }
    __syncthreads();
#pragma unroll
    for (int i = 0; i < 4; i++) {
        int c = ty + i * 16;
        ushort4 v;
        v.x = t[c][tx * 4 + 0]; v.y = t[c][tx * 4 + 1];
        v.z = t[c][tx * 4 + 2]; v.w = t[c][tx * 4 + 3];
        *(ushort4*)(out + (size_t)(c0 + c) * R + r0 + tx * 4) = v;
    }
}

// ---------------------------------------------------------------------------
// 8-way activation blend
// ---------------------------------------------------------------------------
__device__ __forceinline__ float act_blend(float a,
    float w0, float w1, float w2, float w3,
    float w4, float w5, float w6, float w7)
{
    float sig = 1.f / (1.f + expf(-a));
    float elu = (a > 0.f) ? a : (expf(a) - 1.f);
    float th  = tanhf(a);
    float rel = fmaxf(a, 0.f);
    float sil = a * sig;
    float gel = a * 0.5f * (1.f + erff(a * 0.70710678118654752f));
    float sel = (a > 0.f) ? 1.0507009873554805f * a
                          : 1.0507009873554805f * 1.6732632423543772f * (expf(a) - 1.f);
    float sp  = (a > 20.f) ? a : log1pf(expf(a));
    float mish = a * tanhf(sp);
    return w0 * sig + w1 * elu + w2 * th + w3 * rel + w4 * sil + w5 * gel
         + w6 * sel + w7 * mish;
}

// ---------------------------------------------------------------------------
// GEMM-A (8-phase 256^2, split-K): P[z][n,u] partial = y@wmT^T over K-chunk z.
// grid (8, 8, 4), 512 thr, LDS 128 KiB -> 256 blocks, 1/CU.
// ---------------------------------------------------------------------------
__global__ __launch_bounds__(512, 2)
void k_gemm_a8(const u16* __restrict__ A, const u16* __restrict__ B,
               float* __restrict__ P)
{
    __shared__ __align__(16) char lds[131072];
    const int row0 = blockIdx.y * 256, col0 = blockIdx.x * 256;
    const u16* Ac = A + (size_t)blockIdx.z * 1024;
    const u16* Bc = B + (size_t)blockIdx.z * 1024;

    f32x4 acc[8][4];
    gemm256_core8(Ac, Bc, 16, 4096, row0, col0, lds, acc);

    float* Pz = P + (size_t)blockIdx.z * 2048 * 2048;
    const int tid = threadIdx.x, lane = tid & 63, wv = tid >> 6;
    const int wr = wv >> 2, wc = wv & 3, lr = lane & 15, kg = lane >> 4;
#pragma unroll
    for (int i = 0; i < 8; i++)
#pragma unroll
        for (int r = 0; r < 4; r++) {
            int n = row0 + wr * 128 + i * 16 + kg * 4 + r;
            size_t ob = (size_t)n * 2048;
#pragma unroll
            for (int j = 0; j < 4; j++)
                Pz[ob + col0 + wc * 64 + j * 16 + lr] = acc[i][j][r];
        }
}

// ---------------------------------------------------------------------------
// reduce 4 split-K partials + GEMM-A epilogue:
// blend[n,u] = blend8(relu((sum_s P[s][n,u] + gate[n]·b[u])*conn[u]*mask[u]))
// ---------------------------------------------------------------------------
__global__ __launch_bounds__(256)
void k_reduce_blend(const float* __restrict__ P, const float* __restrict__ gate,
                    const float* __restrict__ conn, const float* __restrict__ mask,
                    const float* __restrict__ wts, const float* __restrict__ bbias,
                    u16* __restrict__ blend)
{
    constexpr size_t SL = (size_t)2048 * 2048;
    const int n  = blockIdx.x;
    const int u0 = threadIdx.x * 8;
    const float* base = P + (size_t)n * 2048 + u0;

    float v[8];
#pragma unroll
    for (int h = 0; h < 2; h++) {
        float4 a = *(const float4*)(base + h * 4);
        float4 b = *(const float4*)(base + SL + h * 4);
        float4 c = *(const float4*)(base + 2 * SL + h * 4);
        float4 d = *(const float4*)(base + 3 * SL + h * 4);
        v[h * 4 + 0] = a.x + b.x + c.x + d.x;
        v[h * 4 + 1] = a.y + b.y + c.y + d.y;
        v[h * 4 + 2] = a.z + b.z + c.z + d.z;
        v[h * 4 + 3] = a.w + b.w + c.w + d.w;
    }
    float4 g = *(const float4*)(gate + n * 4);
    const float w0 = wts[0], w1 = wts[1], w2 = wts[2], w3 = wts[3];
    const float w4 = wts[4], w5 = wts[5], w6 = wts[6], w7 = wts[7];

    ushort4 o[2];
#pragma unroll
    for (int j = 0; j < 8; j++) {
        int u = u0 + j;
        float4 b4 = *(const float4*)(bbias + u * 4);
        float z = v[j] + g.x * b4.x + g.y * b4.y + g.z * b4.z + g.w * b4.w;
        float a = fmaxf(z * conn[u] * mask[u], 0.f);
        u16 r = f2b(act_blend(a, w0, w1, w2, w3, w4, w5, w6, w7));
        ((u16*)o)[j] = r;
    }
    *(ushort4*)(blend + (size_t)n * 2048 + u0)     = o[0];
    *(ushort4*)(blend + (size_t)n * 2048 + u0 + 4) = o[1];
}

// ---------------------------------------------------------------------------
// GEMM-B (8-phase 256^2): logits[n,m] = blend@read_W^T + read_b (bf16 out)
// grid (32, 8), 512 thr -> 256 blocks, 1/CU.
// ---------------------------------------------------------------------------
__global__ __launch_bounds__(512, 2)
void k_gemm_logits8(const u16* __restrict__ BL, const u16* __restrict__ RWT,
                    const float* __restrict__ rbias, u16* __restrict__ out)
{
    __shared__ __align__(16) char lds[131072];
    const int row0 = blockIdx.y * 256, col0 = blockIdx.x * 256;

    f32x4 acc[8][4];
    gemm256_core8(BL, RWT, 32, 2048, row0, col0, lds, acc);

    const int tid = threadIdx.x, lane = tid & 63, wv = tid >> 6;
    const int wr = wv >> 2, wc = wv & 3, lr = lane & 15, kg = lane >> 4;
    float rb[4]; int mm[4];
#pragma unroll
    for (int j = 0; j < 4; j++) {
        mm[j] = col0 + wc * 64 + j * 16 + lr;
        rb[j] = rbias[mm[j]];
    }
#pragma unroll
    for (int i = 0; i < 8; i++)
#pragma unroll
        for (int r = 0; r < 4; r++) {
            int n = row0 + wr * 128 + i * 16 + kg * 4 + r;
            size_t ob = (size_t)n * 8192;
#pragma unroll
            for (int j = 0; j < 4; j++)
                out[ob + mm[j]] = f2b(acc[i][j][r] + rb[j]);
        }
}

// ---------------------------------------------------------------------------
// in-place row softmax over 8192 bf16 (one block per row, values in registers)
// ---------------------------------------------------------------------------
__global__ __launch_bounds__(256)
void k_softmax(u16* __restrict__ buf)
{
    __shared__ float red[8];
    const int tid = threadIdx.x, lane = tid & 63, wv = tid >> 6;
    u16* row = buf + (size_t)blockIdx.x * 8192;
    float v[32];
    float mx = -1e30f;
#pragma unroll
    for (int s = 0; s < 8; s++) {
        ushort4 u4 = *(const ushort4*)(row + (s * 256 + tid) * 4);
        float a = b2f(u4.x), b = b2f(u4.y), c = b2f(u4.z), d = b2f(u4.w);
        v[s * 4 + 0] = a; v[s * 4 + 1] = b; v[s * 4 + 2] = c; v[s * 4 + 3] = d;
        mx = fmaxf(mx, fmaxf(fmaxf(a, b), fmaxf(c, d)));
    }
#pragma unroll
    for (int off = 32; off > 0; off >>= 1) mx = fmaxf(mx, __shfl_xor(mx, off));
    if (lane == 0) red[wv] = mx;
    __syncthreads();
    mx = fmaxf(fmaxf(red[0], red[1]), fmaxf(red[2], red[3]));
    float sum = 0.f;
#pragma unroll
    for (int k = 0; k < 32; k++) { v[k] = expf(v[k] - mx); sum += v[k]; }
#pragma unroll
    for (int off = 32; off > 0; off >>= 1) sum += __shfl_xor(sum, off);
    if (lane == 0) red[4 + wv] = sum;
    __syncthreads();
    float inv = 1.f / (red[4] + red[5] + red[6] + red[7]);
#pragma unroll
    for (int s = 0; s < 8; s++) {
        ushort4 o;
        o.x = f2b(v[s * 4 + 0] * inv); o.y = f2b(v[s * 4 + 1] * inv);
        o.z = f2b(v[s * 4 + 2] * inv); o.w = f2b(v[s * 4 + 3] * inv);
        *(ushort4*)(row + (s * 256 + tid) * 4) = o;
    }
}

// ---------------------------------------------------------------------------
// GEMM-C (2-phase 128^2 split-K, S=2): P[z][n,md] partial = attn @ mem chunk.
// ---------------------------------------------------------------------------
template<int BM, int BN, int S, int NCOL>
__global__ __launch_bounds__(256, 4)
void k_gemm_partial(const u16* __restrict__ A, const u16* __restrict__ B,
                    int Kchunk, int ld, float* __restrict__ P)
{
    constexpr int MT = BM / 32, NT = BN / 32;
    __shared__ __align__(16) u16 smem[2 * (BM + BN) * 32 * S];

    const int nx = gridDim.x, ny = gridDim.y;
    const int f  = blockIdx.x + nx * blockIdx.y;
    const int ch = (nx * ny) >> 3;                 // chunk per XCD
    const int sw = (f & 7) * ch + (f >> 3);        // bijective (nwg%8==0)
    const int bx = sw % nx, by = sw / nx;
    const int row0 = by * BM, col0 = bx * BN;

    const u16* Ac = A + (size_t)blockIdx.z * Kchunk;
    const u16* Bc = B + (size_t)blockIdx.z * Kchunk;

    f32x4 acc[MT][NT];
    gemm_core_db<BM, BN, S>(Ac, Bc, Kchunk, ld, row0, col0, smem, acc);

    float* Pz = P + (size_t)blockIdx.z * 2048 * NCOL;
    const int tid = threadIdx.x, lane = tid & 63, wv = tid >> 6;
    const int wr = wv >> 1, wc = wv & 1, lr = lane & 15, kg = lane >> 4;
#pragma unroll
    for (int i = 0; i < MT; i++)
#pragma unroll
        for (int r = 0; r < 4; r++) {
            int n = row0 + wr * (BM / 2) + i * 16 + kg * 4 + r;
            size_t ob = (size_t)n * NCOL;
#pragma unroll
            for (int j = 0; j < NT; j++)
                Pz[ob + col0 + wc * (BN / 2) + j * 16 + lr] = acc[i][j][r];
        }
}

// ---------------------------------------------------------------------------
// reduce 4 split-K partials into final f32 output (GEMM-C tail)
// ---------------------------------------------------------------------------
__global__ __launch_bounds__(256)
void k_reduce_out(const float* __restrict__ P, float* __restrict__ out)
{
    constexpr size_t SL = (size_t)2048 * 1024;
    size_t i = ((size_t)blockIdx.x * 256 + threadIdx.x) * 4;
    float4 a = *(const float4*)(P + i);
    float4 b = *(const float4*)(P + SL + i);
    float4 c = *(const float4*)(P + 2 * SL + i);
    float4 d = *(const float4*)(P + 3 * SL + i);
    float4 o;
    o.x = a.x + b.x + c.x + d.x;
    o.y = a.y + b.y + c.y + d.y;
    o.z = a.z + b.z + c.z + d.z;
    o.w = a.w + b.w + c.w + d.w;
    *(float4*)(out + i) = o;
}

// sentinel: distinctive output if workspace is too small (absmax ~12345)
__global__ void k_fill(float* out, int n)
{
    int i = blockIdx.x * 256 + threadIdx.x;
    if (i < n) out[i] = 12345.f;
}

// ---------------------------------------------------------------------------
extern "C" void kernel_launch(void* const* d_in, const int* in_sizes, int n_in,
                              void* d_out, int out_size, void* d_ws, size_t ws_size,
                              hipStream_t stream)
{
    const float* x     = (const float*)d_in[0];
    const float* w     = (const float*)d_in[1];
    const float* delay = (const float*)d_in[2];
    const float* bb    = (const float*)d_in[3];
    const float* gW    = (const float*)d_in[4];
    const float* gb    = (const float*)d_in[5];
    const float* na    = (const float*)d_in[6];
    const float* cW1   = (const float*)d_in[7];
    const float* cb1   = (const float*)d_in[8];
    const float* cW2   = (const float*)d_in[9];
    const float* cb2   = (const float*)d_in[10];
    const float* mask  = (const float*)d_in[11];
    const float* actw  = (const float*)d_in[12];
    const float* rW    = (const float*)d_in[13];
    const float* rb    = (const float*)d_in[14];
    const float* mem   = (const float*)d_in[15];
    (void)in_sizes; (void)n_in;

    char* ws = (char*)d_ws;
    size_t off = 0;
    auto alloc = [&](size_t bytes) {
        size_t o = off; off += (bytes + 255) & ~(size_t)255; return o;
    };
    size_t o_wts   = alloc(9 * 4);
    size_t o_gate  = alloc(2048 * 4 * 4);
    size_t o_conn  = alloc(2048 * 4);
    size_t o_y     = alloc((size_t)2048 * 4096 * 2);   // y; later aliased as memT
    size_t o_wmT   = alloc((size_t)2048 * 4096 * 2);
    size_t o_blend = alloc((size_t)2048 * 2048 * 2);
    size_t o_rwT   = alloc((size_t)8192 * 2048 * 2);   // rwT; also split-K partials
    size_t o_log   = alloc((size_t)2048 * 8192 * 2);   // logits; A-partials overflow

    if (off > ws_size) {   // loud, distinguishable failure mode
        k_fill<<<(out_size + 255) / 256, 256, 0, stream>>>((float*)d_out, out_size);
        return;
    }

    float* wts   = (float*)(ws + o_wts);
    float* gate  = (float*)(ws + o_gate);
    float* conn  = (float*)(ws + o_conn);
    u16* y       = (u16*)(ws + o_y);
    u16* wmT     = (u16*)(ws + o_wmT);
    u16* blend   = (u16*)(ws + o_blend);
    u16* rwT     = (u16*)(ws + o_rwT);
    u16* logits  = (u16*)(ws + o_log);
    u16* memT    = y;   // y dead after GEMM-A; same size (16 MB)

    // split-K partial buffers, aliased into lifetime holes:
    //   A-partials: 4 x 2048 x 2048 f32 = 64 MB @ [o_rwT, o_rwT+64MB)
    //     (rwT written AFTER reduce_blend; logits written AFTER that) — no overlap.
    //   C-partials: 4 x 2048 x 1024 f32 = 32 MB @ o_rwT (rwT dead after logits).
    float* pA = (float*)(ws + o_rwT);
    float* pC = (float*)(ws + o_rwT);

    k_small<<<1, 256, 0, stream>>>(na, cW1, cb1, cW2, cb2, actw, conn, wts);
    k_gate_y<<<512, 256, 0, stream>>>(x, gW, gb, gate, y);
    k_wmT<<<dim3(32, 32), 256, 0, stream>>>(w, delay, wmT);

    // GEMM-A: partials = y[2048,4096] @ wmT[2048,4096]^T, split-K=4 (K=1024 each)
    k_gemm_a8<<<dim3(8, 8, 4), 512, 0, stream>>>(y, wmT, pA);
    k_reduce_blend<<<2048, 256, 0, stream>>>(pA, gate, conn, mask, wts, bb, blend);

    k_transpose<<<dim3(128, 32), 256, 0, stream>>>(rW, rwT, 2048, 8192);
    k_gemm_logits8<<<dim3(32, 8), 512, 0, stream>>>(blend, rwT, rb, logits);
    k_softmax<<<2048, 256, 0, stream>>>(logits);

    k_transpose<<<dim3(16, 128), 256, 0, stream>>>(mem, memT, 8192, 1024);

    // GEMM-C: out-partials = attn[2048,8192] @ memT[1024,8192]^T, split-K=4 (K=2048)
    k_gemm_partial<128, 128, 2, 1024><<<dim3(8, 16, 4), 256, 0, stream>>>(
        logits, memT, 2048, 8192, pC);
    k_reduce_out<<<2048, 256, 0, stream>>>(pC, (float*)d_out);
}